// Round 11
// baseline (783.487 us; speedup 1.0000x reference)
//
#include <hip/hip_runtime.h>

// EncodingBlock — Round 11: multi-t blocks for k1 and k3 (phase math = round-10
// verbatim). One block = (n, 8 consecutive t) looping over the same LDS:
//  * kills dispatch-batch quantization (k1: 9.14 batches -> 1.14; k3: 8 -> 1)
//  * x (k1) / saB+x (k3) for t+1 prefetched into registers during t's compute
//  * k1: ln_g/ln_b in registers (old LDS slot was overlay-clobbered per t)
//  * extra end-of-t barrier protects featT/sPart (k1) rewrite vs P5/P6 reads
// k5/k7/kpart/kreduce/kprepack unchanged from round-10 (measured best).

#define EPS 1e-5f

typedef __bf16 bf16;
typedef __bf16 bf16x8 __attribute__((ext_vector_type(8)));
typedef float f32x4 __attribute__((ext_vector_type(4)));

// ------------------------------------------------------------------
// Prepack weights to MFMA B-fragments.
// ------------------------------------------------------------------
__global__ void kprepack(const float* __restrict__ qk_w, const float* __restrict__ convd_w,
                         const float* __restrict__ w1g,
                         bf16* __restrict__ qkB, bf16* __restrict__ convB, bf16* __restrict__ w1B)
{
  int gid = blockIdx.x * 256 + threadIdx.x;
  if (gid < 384) {                       // qk: (nt,ks,lane) 3*2*64, hi/lo
    int lane = gid & 63, f = gid >> 6;
    int nt = f >> 1, ks = f & 1;
    int row = nt * 16 + (lane & 15);
    int col = ks * 32 + ((lane >> 4) * 8);
    const float* src = &qk_w[row * 64 + col];
    bf16* dh = &qkB[(f * 64 + lane) * 8];
    bf16* dl = dh + 3072;
    #pragma unroll
    for (int j = 0; j < 8; j++) {
      float w = src[j];
      bf16 h = (bf16)w;
      dh[j] = h;
      dl[j] = (bf16)(w - (float)h);
    }
  } else if (gid < 1920) {               // convd: (nt,ks,lane) 4*6*64
    int g = gid - 384;
    int lane = g & 63, f = g >> 6;
    int nt = f / 6, ks = f - nt * 6;
    int k0 = ks * 32 + ((lane >> 4) * 8);
    int h = k0 >> 6, c = k0 & 63;
    int o = nt * 16 + (lane & 15);
    const float* src = &convd_w[(h * 64 + o) * 64 + c];
    bf16* d = &convB[(f * 64 + lane) * 8];
    #pragma unroll
    for (int j = 0; j < 8; j++) d[j] = (bf16)src[j];
  } else if (gid < 2432) {               // w1: (nt,ks,lane) 4*2*64, hi/lo
    int g = gid - 1920;
    int lane = g & 63, f = g >> 6;
    int nt = f >> 1, ks = f & 1;
    int ko = nt * 16 + (lane & 15);
    int c0 = ks * 32 + ((lane >> 4) * 8);
    const float* src = &w1g[ko * 64 + c0];
    bf16* dh = &w1B[(f * 64 + lane) * 8];
    bf16* dl = dh + 4096;
    #pragma unroll
    for (int j = 0; j < 8; j++) {
      float w = src[j];
      bf16 h = (bf16)w;
      dh[j] = h;
      dl[j] = (bf16)(w - (float)h);
    }
  }
}

// ------------------------------------------------------------------
// Kernel 1: fused SelfAttention + SA_GC (pre-BN). LDS 21.5 KB -> 7/CU.
// Multi-t: block = (tc, n), loops t = tc*8 .. tc*8+7 with x prefetch.
// ------------------------------------------------------------------
__global__ __launch_bounds__(256, 7)
void k1_sa_sagc(const float* __restrict__ x,
                const float* __restrict__ topo,
                const float* __restrict__ ln_g, const float* __restrict__ ln_b,
                const float* __restrict__ qk_b,
                const bf16* __restrict__ qkB, const bf16* __restrict__ convB,
                const float* __restrict__ convd_b,
                bf16* __restrict__ saB, float* __restrict__ pSum, float* __restrict__ pSq)
{
  const int tc = blockIdx.x, n = blockIdx.y, tid = threadIdx.x;
  const int lane = tid & 63, wave = tid >> 6;
  const int rr = lane & 15, co = (lane >> 4) * 8, rq = (lane >> 4) * 4;

  __shared__ __align__(16) float smem[5512];
  bf16*  featT  = (bf16*)smem;               // [64][40] bf16     [0,1280)
  float* yF     = smem + 1280;               // [25][69] f32      [1280,3005)  slot B
  bf16*  sAttn  = (bf16*)(smem + 1280);      // [75][40] bf16     overlay of yF (P4-P5)
  float* sPartS = smem + 3008;               // [25*4]            slot C
  float* sPartQ = smem + 3208;
  float* sQK    = smem + 3008;               // [25][56] f32      overlay (P3-P4)
  bf16*  zL     = (bf16*)(smem + 3008);      // [25][200] bf16    overlay (P5-P6)

  const int v = tid & 31, cb = tid >> 5;

  // LN gamma/beta in registers (thread owns channels cb+8k)
  float lng[8], lnb[8];
  #pragma unroll
  for (int k = 0; k < 8; k++) { lng[k] = ln_g[cb + 8 * k]; lnb[k] = ln_b[cb + 8 * k]; }

  // initial x load (t = tc*8)
  float xv[8];
  {
    const float* xp = &x[((n * 64 + cb) * 512 + tc * 8) * 25 + (v < 25 ? v : 0)];
    #pragma unroll
    for (int k = 0; k < 8; k++) xv[k] = (v < 25) ? xp[k * 102400] : 0.f;  // 102400 = 8*512*25
  }

  #pragma unroll 1
  for (int tl = 0; tl < 8; tl++) {
    const int t = tc * 8 + tl;
    const int blk = n * 512 + t;

    // P1: featT bf16 writes + LN partials (from registers)
    {
      float s = 0.f, q = 0.f;
      #pragma unroll
      for (int k = 0; k < 8; k++) {
        float f = xv[k];
        featT[(cb + 8 * k) * 40 + v] = (bf16)f;   // v>=25 lanes write the zero pad
        s += f; q += f * f;
      }
      s += __shfl_xor(s, 32); q += __shfl_xor(q, 32);
      if (lane < 32 && v < 25) { sPartS[v * 4 + wave] = s; sPartQ[v * 4 + wave] = q; }
    }
    // prefetch x for t+1 (overlaps P2..P6 compute)
    float xn[8];
    if (tl < 7) {
      const float* xp = &x[((n * 64 + cb) * 512 + t + 1) * 25 + (v < 25 ? v : 0)];
      #pragma unroll
      for (int k = 0; k < 8; k++) xn[k] = (v < 25) ? xp[k * 102400] : 0.f;
    }
    __syncthreads();

    // P2: finalize LN stats (redundant per thread) + y -> yF f32 (conflict-free)
    if (v < 25) {
      float S = sPartS[v * 4] + sPartS[v * 4 + 1] + sPartS[v * 4 + 2] + sPartS[v * 4 + 3];
      float Q = sPartQ[v * 4] + sPartQ[v * 4 + 1] + sPartQ[v * 4 + 2] + sPartQ[v * 4 + 3];
      float mu = S * (1.f / 64.f);
      float rstd = rsqrtf(Q * (1.f / 64.f) - mu * mu + EPS);
      #pragma unroll
      for (int k = 0; k < 8; k++) {
        int c = cb + 8 * k;
        yF[v * 69 + c] = (xv[k] - mu) * rstd * lng[k] + lnb[k];
      }
    }
    __syncthreads();

    // P3: QK projection via MFMA; hi/lo split computed in-register from yF.
    {
      const int mt = wave & 1;
      const int r0 = mt * 16 + rr;               // rows >=25 read junk -> discarded C rows
      bf16x8 Ah[2], Al[2];
      #pragma unroll
      for (int ks = 0; ks < 2; ks++) {
        const float* yp = &yF[r0 * 69 + ks * 32 + co];
        #pragma unroll
        for (int j = 0; j < 8; j++) {
          float yv = yp[j];
          bf16 h = (bf16)yv;
          Ah[ks][j] = h;
          Al[ks][j] = (bf16)(yv - (float)h);
        }
      }
      #pragma unroll
      for (int q = 0; q < 2; q++) {
        if (wave >= 2 && q > 0) break;
        int nt = (wave < 2) ? (q * 2) : 1;
        float qb = qk_b[nt * 16 + rr];
        f32x4 acc = {qb, qb, qb, qb};
        #pragma unroll
        for (int ks = 0; ks < 2; ks++) {
          bf16x8 Bh = *(const bf16x8*)&qkB[((nt * 2 + ks) * 64 + lane) * 8];
          bf16x8 Bl = *(const bf16x8*)&qkB[3072 + ((nt * 2 + ks) * 64 + lane) * 8];
          acc = __builtin_amdgcn_mfma_f32_16x16x32_bf16(Ah[ks], Bh, acc, 0, 0, 0);
          acc = __builtin_amdgcn_mfma_f32_16x16x32_bf16(Ah[ks], Bl, acc, 0, 0, 0);
          acc = __builtin_amdgcn_mfma_f32_16x16x32_bf16(Al[ks], Bh, acc, 0, 0, 0);
        }
        #pragma unroll
        for (int r = 0; r < 4; r++) {
          int i = mt * 16 + rq + r;
          if (i < 25) sQK[i * 56 + nt * 16 + rr] = acc[r];
        }
      }
    }
    __syncthreads();

    // P4: dots + softmax + *topo -> sAttn bf16 [75][40]; 2 threads per (h,i) row
    if (tid < 150) {
      int p = tid >> 1, half = tid & 1;
      int h = p / 25, i = p - (p / 25) * 25;
      const float* qr = &sQK[i * 56 + h * 8];
      float4 qa = *(const float4*)qr, qb4 = *(const float4*)(qr + 4);
      const int j0 = half * 13;
      const int cnt = 13 - half;
      float lgv[13];
      float lmax = -3.4e38f;
      #pragma unroll
      for (int jj = 0; jj < 13; jj++) {
        int j = j0 + jj; j = j > 24 ? 24 : j;
        const float* kr = &sQK[j * 56 + 24 + h * 8];
        float4 ka = *(const float4*)kr, kb = *(const float4*)(kr + 4);
        float d = qa.x * ka.x + qa.y * ka.y + qa.z * ka.z + qa.w * ka.w
                + qb4.x * kb.x + qb4.y * kb.y + qb4.z * kb.z + qb4.w * kb.w;
        d *= 0.35355339059327373f;
        lgv[jj] = d;
        lmax = fmaxf(lmax, d);
      }
      lmax = fmaxf(lmax, __shfl_xor(lmax, 1));
      float se = 0.f;
      #pragma unroll
      for (int jj = 0; jj < 13; jj++) {
        float e = __expf(lgv[jj] - lmax);
        lgv[jj] = e;
        if (jj < cnt) se += e;
      }
      se += __shfl_xor(se, 1);
      float inv = 1.f / se;
      bf16* ar = &sAttn[(h * 25 + i) * 40];
      #pragma unroll
      for (int jj = 0; jj < 13; jj++) {
        int j = j0 + jj;
        if (jj < cnt) ar[j] = (bf16)(lgv[jj] * inv * topo[(h * 25 + i) * 25 + j]);
      }
      if (half) {
        #pragma unroll
        for (int j = 25; j < 32; j++) ar[j] = (bf16)0.f;   // K-dim pad must be zero
      }
    }
    __syncthreads();

    // P5: z = A_h @ feat via MFMA; wave owns 16 feat-cols; zL [25][200]
    {
      const int nt = wave;
      bf16x8 Bf = *(const bf16x8*)&featT[(nt * 16 + rr) * 40 + co];
      #pragma unroll
      for (int h = 0; h < 3; h++) {
        #pragma unroll
        for (int mt = 0; mt < 2; mt++) {
          bf16x8 Af = *(const bf16x8*)&sAttn[(h * 25 + mt * 16 + rr) * 40 + co];
          f32x4 az = {0.f, 0.f, 0.f, 0.f};
          az = __builtin_amdgcn_mfma_f32_16x16x32_bf16(Af, Bf, az, 0, 0, 0);
          #pragma unroll
          for (int r = 0; r < 4; r++) {
            int i = mt * 16 + rq + r;
            if (i < 25) zL[i * 200 + h * 64 + nt * 16 + rr] = (bf16)az[r];
          }
        }
      }
    }
    __syncthreads();

    // P6: sa = z @ Wcat via MFMA; direct global store + shfl BN partials
    {
      const int nt = wave;
      int o = nt * 16 + rr;
      float cb2 = convd_b[o] + convd_b[64 + o] + convd_b[128 + o];
      float po = 0.f, pq = 0.f;
      #pragma unroll
      for (int mt = 0; mt < 2; mt++) {
        int zr = mt * 16 + rr;
        zr = (zr < 25) ? zr : 0;                 // clamp: stay inside zL allocation
        f32x4 acc = {cb2, cb2, cb2, cb2};
        #pragma unroll
        for (int ks = 0; ks < 6; ks++) {
          bf16x8 Az = *(const bf16x8*)&zL[zr * 200 + ks * 32 + co];
          bf16x8 Bw = *(const bf16x8*)&convB[((nt * 6 + ks) * 64 + lane) * 8];
          acc = __builtin_amdgcn_mfma_f32_16x16x32_bf16(Az, Bw, acc, 0, 0, 0);
        }
        #pragma unroll
        for (int r = 0; r < 4; r++) {
          int i = mt * 16 + rq + r;
          if (i < 25) {
            float val = acc[r];
            saB[blk * 1600 + o * 25 + i] = (bf16)val;
            po += val; pq += val * val;
          }
        }
      }
      po += __shfl_xor(po, 16); pq += __shfl_xor(pq, 16);
      po += __shfl_xor(po, 32); pq += __shfl_xor(pq, 32);
      if (lane < 16) {
        pSum[blk * 64 + o] = po;
        pSq [blk * 64 + o] = pq;
      }
    }
    __syncthreads();   // protect featT/sPart (overlays zL head) rewrite next t

    if (tl < 7) {
      #pragma unroll
      for (int k = 0; k < 8; k++) xv[k] = xn[k];
    }
  }
}

// ------------------------------------------------------------------
// kpart: coalesced first-level reduce of [16384][64] partials -> [256][64]
// ------------------------------------------------------------------
__global__ __launch_bounds__(256, 8)
void kpart(const float* __restrict__ pS, const float* __restrict__ pQ,
           float* __restrict__ oS, float* __restrict__ oQ)
{
  const int g = blockIdx.x, tid = threadIdx.x;
  const int c = tid & 63, r = tid >> 6;
  float s = 0.f, q = 0.f;
  for (int i = 0; i < 16; i++) {
    int b = g * 64 + r * 16 + i;
    s += pS[b * 64 + c]; q += pQ[b * 64 + c];
  }
  __shared__ float ls[4][64], lq[4][64];
  ls[r][c] = s; lq[r][c] = q;
  __syncthreads();
  if (tid < 64) {
    oS[g * 64 + tid] = ls[0][tid] + ls[1][tid] + ls[2][tid] + ls[3][tid];
    oQ[g * 64 + tid] = lq[0][tid] + lq[1][tid] + lq[2][tid] + lq[3][tid];
  }
}

// ------------------------------------------------------------------
// BN-stat reduce: one block per channel; partials layout [part][C]
// ------------------------------------------------------------------
__global__ __launch_bounds__(256, 4)
void kreduce(const float* __restrict__ pS, const float* __restrict__ pQ,
             int npart, int C, float invN,
             const float* __restrict__ g, const float* __restrict__ bta,
             float* __restrict__ sc, float* __restrict__ sh)
{
  int c = blockIdx.x, tid = threadIdx.x;
  float s = 0.f, q = 0.f;
  for (int i = tid; i < npart; i += 256) { s += pS[i * C + c]; q += pQ[i * C + c]; }
  #pragma unroll
  for (int m = 1; m < 64; m <<= 1) { s += __shfl_xor(s, m); q += __shfl_xor(q, m); }
  __shared__ float rs[4], rq[4];
  int w = tid >> 6;
  if ((tid & 63) == 0) { rs[w] = s; rq[w] = q; }
  __syncthreads();
  if (tid == 0) {
    float S = rs[0] + rs[1] + rs[2] + rs[3];
    float Q = rq[0] + rq[1] + rq[2] + rq[3];
    float mu = S * invN, var = Q * invN - mu * mu;
    float r = rsqrtf(var + EPS);
    sc[c] = g[c] * r;
    sh[c] = bta[c] - mu * g[c] * r;
  }
}

// ------------------------------------------------------------------
// Kernel 3: y_gc = relu(bn(sa)+x); pre = y_gc @ W1 + b1 via MFMA (hi/lo)
// Multi-t: block = (tc, n), loops 8 t's; saB/x prefetched into registers.
// ------------------------------------------------------------------
__global__ __launch_bounds__(256, 8)
void k3_ygc_pre(const float* __restrict__ x, const bf16* __restrict__ saB,
                const float* __restrict__ scS, const float* __restrict__ shS,
                const bf16* __restrict__ w1B, const float* __restrict__ b1,
                bf16* __restrict__ preB, float* __restrict__ pSum, float* __restrict__ pSq)
{
  const int tc = blockIdx.x, n = blockIdx.y, tid = threadIdx.x;
  const int lane = tid & 63, wave = tid >> 6;
  const int rr = lane & 15, co = (lane >> 4) * 8, rq = (lane >> 4) * 4;

  __shared__ __align__(16) float smem[3656];
  bf16*  yH   = (bf16*)smem;             // [25][72] bf16 -> [0, 900)
  bf16*  yL   = (bf16*)(smem + 900);     // [900, 1800)
  float* sPre = smem + 1800;             // [64][29] [1800, 3656)

  const int lin = (tid < 200) ? tid * 8 : 0;
  const int c0 = lin / 25, v0 = lin - c0 * 25;

  // initial prefetch (t = tc*8)
  bf16x8 s8 = {};
  float x8[8];
  if (tid < 200) {
    int blk0 = n * 512 + tc * 8;
    s8 = *(const bf16x8*)&saB[blk0 * 1600 + lin];
    int c = c0, v = v0;
    #pragma unroll
    for (int e = 0; e < 8; e++) {
      x8[e] = x[((n * 64 + c) * 512 + tc * 8) * 25 + v];
      if (++v == 25) { v = 0; c++; }
    }
  }

  #pragma unroll 1
  for (int tl = 0; tl < 8; tl++) {
    const int t = tc * 8 + tl;
    const int blk = n * 512 + t;

    // P1: yH/yL from registers
    if (tid < 200) {
      int c = c0, v = v0;
      #pragma unroll
      for (int e = 0; e < 8; e++) {
        float val = scS[c] * (float)s8[e] + shS[c] + x8[e];
        val = fmaxf(val, 0.f);
        bf16 h = (bf16)val;
        yH[v * 72 + c] = h;
        yL[v * 72 + c] = (bf16)(val - (float)h);
        if (++v == 25) { v = 0; c++; }
      }
    }
    // prefetch t+1 (overlaps MFMA phase)
    bf16x8 s8n = {};
    float x8n[8];
    if (tl < 7 && tid < 200) {
      s8n = *(const bf16x8*)&saB[(blk + 1) * 1600 + lin];
      int c = c0, v = v0;
      #pragma unroll
      for (int e = 0; e < 8; e++) {
        x8n[e] = x[((n * 64 + c) * 512 + t + 1) * 25 + v];
        if (++v == 25) { v = 0; c++; }
      }
    }
    __syncthreads();

    // P2: MFMA (hi/lo)
    {
      const int nt = wave;  // output cols nt*16..+15
      bf16x8 Ah[2][2], Al[2][2];
      #pragma unroll
      for (int mt = 0; mt < 2; mt++) {
        int r0 = mt * 16 + rr;               // rows >=25 read junk -> discarded
        #pragma unroll
        for (int ks = 0; ks < 2; ks++) {
          Ah[mt][ks] = *(const bf16x8*)&yH[r0 * 72 + ks * 32 + co];
          Al[mt][ks] = *(const bf16x8*)&yL[r0 * 72 + ks * 32 + co];
        }
      }
      float bb = b1[nt * 16 + rr];
      #pragma unroll
      for (int mt = 0; mt < 2; mt++) {
        f32x4 acc = {bb, bb, bb, bb};
        #pragma unroll
        for (int ks = 0; ks < 2; ks++) {
          bf16x8 Bh = *(const bf16x8*)&w1B[((nt * 2 + ks) * 64 + lane) * 8];
          bf16x8 Bl = *(const bf16x8*)&w1B[4096 + ((nt * 2 + ks) * 64 + lane) * 8];
          acc = __builtin_amdgcn_mfma_f32_16x16x32_bf16(Ah[mt][ks], Bh, acc, 0, 0, 0);
          acc = __builtin_amdgcn_mfma_f32_16x16x32_bf16(Ah[mt][ks], Bl, acc, 0, 0, 0);
          acc = __builtin_amdgcn_mfma_f32_16x16x32_bf16(Al[mt][ks], Bh, acc, 0, 0, 0);
        }
        #pragma unroll
        for (int r = 0; r < 4; r++) {
          int i = mt * 16 + rq + r;
          if (i < 25) sPre[(nt * 16 + rr) * 29 + i] = acc[r];
        }
      }
    }
    __syncthreads();

    // P3: store preB + BN partials
    if (tid < 200) {
      bf16x8 p8;
      int ko = c0, v = v0;
      #pragma unroll
      for (int e = 0; e < 8; e++) {
        p8[e] = (bf16)sPre[ko * 29 + v];
        if (++v == 25) { v = 0; ko++; }
      }
      *(bf16x8*)&preB[blk * 1600 + lin] = p8;
    }
    if (tid < 64) {
      float s = 0.f, q = 0.f;
      #pragma unroll
      for (int i = 0; i < 25; i++) { float vv = sPre[tid * 29 + i]; s += vv; q += vv * vv; }
      pSum[blk * 64 + tid] = s;
      pSq [blk * 64 + tid] = q;
    }
    // no extra barrier needed: next P1 writes yH/yL (all waves passed post-P2
    // barrier => P2 reads done); P2(t+1) is fenced from P3(t) by post-P1 barrier.

    if (tl < 7 && tid < 200) {
      s8 = s8n;
      #pragma unroll
      for (int e = 0; e < 8; e++) x8[e] = x8n[e];
    }
  }
}

// ------------------------------------------------------------------
// Kernel 5: TCN branches; preB [n][t][ch][v], zbB [b][n][t][o][v]
// Single-stage 16-ch staging (44KB LDS, 3 blocks/CU) — measured best.
// ------------------------------------------------------------------
template<int D>
__device__ __forceinline__ void conv5(const float* __restrict__ sIn, const float* __restrict__ sW,
                                      float4 bias, int o4, int v, int tb, float acc[8][4])
{
  #pragma unroll
  for (int s = 0; s < 8; s++) {
    acc[s][0] = bias.x; acc[s][1] = bias.y; acc[s][2] = bias.z; acc[s][3] = bias.w;
  }
  const int NW = 8 + 4 * D;
  for (int ic = 0; ic < 16; ic++) {
    float4 wk[5];
    #pragma unroll
    for (int kt = 0; kt < 5; kt++) wk[kt] = *(const float4*)&sW[(ic * 5 + kt) * 16 + o4];
    float xw[8 + 4 * D];
    #pragma unroll
    for (int w = 0; w < NW; w++) xw[w] = sIn[(ic * 24 + (tb - 2 * D + w + 4)) * 25 + v];
    #pragma unroll
    for (int s = 0; s < 8; s++)
      #pragma unroll
      for (int kt = 0; kt < 5; kt++) {
        float xv = xw[s + kt * D];
        acc[s][0] += xv * wk[kt].x; acc[s][1] += xv * wk[kt].y;
        acc[s][2] += xv * wk[kt].z; acc[s][3] += xv * wk[kt].w;
      }
  }
}

__global__ __launch_bounds__(256, 3)
void k5_tcn_branch(const bf16* __restrict__ preB,
                   const float* __restrict__ sc1, const float* __restrict__ sh1,
                   const float* __restrict__ w2, const float* __restrict__ b2,
                   bf16* __restrict__ zbB, float* __restrict__ pSum2, float* __restrict__ pSq2)
{
  const int tt = blockIdx.x, b = blockIdx.y, n = blockIdx.z;
  const int tid = threadIdx.x, t0 = tt * 16;
  __shared__ __align__(16) float sIn[16 * 24 * 25];
  __shared__ __align__(16) float sW[16 * 5 * 16];
  __shared__ float sRedS[4][4][4], sRedQ[4][4][4];

  for (int idx = tid; idx < 1200; idx += 256) {
    int r = idx / 50, k8 = idx - r * 50;
    int gt = t0 - 4 + r;
    int lin = k8 * 8;
    if (gt >= 0 && gt < 512) {
      bf16x8 p8 = *(const bf16x8*)&preB[((n * 512 + gt) * 64 + b * 16) * 25 + lin];
      #pragma unroll
      for (int e = 0; e < 8; e++) {
        int q = lin + e, ic = q / 25, v = q - ic * 25;
        int ch = b * 16 + ic;
        sIn[(ic * 24 + r) * 25 + v] = fmaxf(sc1[ch] * (float)p8[e] + sh1[ch], 0.f);
      }
    } else {
      #pragma unroll
      for (int e = 0; e < 8; e++) {
        int q = lin + e, ic = q / 25, v = q - ic * 25;
        sIn[(ic * 24 + r) * 25 + v] = 0.f;
      }
    }
  }
  if (b < 2)
    for (int idx = tid; idx < 1280; idx += 256) {
      int o = idx / 80, rem = idx - o * 80;
      int ic = rem / 5, kt = rem - ic * 5;
      sW[(ic * 5 + kt) * 16 + o] = w2[((b * 16 + o) * 16 + ic) * 5 + kt];
    }
  __syncthreads();

  float po[4] = {0.f, 0.f, 0.f, 0.f}, pq[4] = {0.f, 0.f, 0.f, 0.f};
  if (tid < 200) {
    int tx = tid & 3, o4 = tx * 4;
    int g = tid >> 2;
    int v = g % 25, th = g / 25;
    int tb = th * 8;
    float acc[8][4];
    if (b == 0)      conv5<1>(sIn, sW, *(const float4*)&b2[o4],      o4, v, tb, acc);
    else if (b == 1) conv5<2>(sIn, sW, *(const float4*)&b2[16 + o4], o4, v, tb, acc);
    else {
      #pragma unroll
      for (int s = 0; s < 8; s++)
        #pragma unroll
        for (int j = 0; j < 4; j++) {
          int o = o4 + j, r = tb + s + 4;
          float a = sIn[(o * 24 + r - 1) * 25 + v];
          float m = sIn[(o * 24 + r    ) * 25 + v];
          float c = sIn[(o * 24 + r + 1) * 25 + v];
          acc[s][j] = fmaxf(fmaxf(a, m), c);
        }
    }
    #pragma unroll
    for (int s = 0; s < 8; s++) {
      int gt = t0 + tb + s;
      #pragma unroll
      for (int j = 0; j < 4; j++) {
        float val = acc[s][j];
        zbB[(((b * 32 + n) * 512 + gt) * 16 + (o4 + j)) * 25 + v] = (bf16)val;
        po[j] += val; pq[j] += val * val;
      }
    }
  }
  #pragma unroll
  for (int m = 4; m < 64; m <<= 1) {
    #pragma unroll
    for (int j = 0; j < 4; j++) { po[j] += __shfl_xor(po[j], m); pq[j] += __shfl_xor(pq[j], m); }
  }
  int lane = tid & 63, w = tid >> 6;
  if (lane < 4) {
    #pragma unroll
    for (int j = 0; j < 4; j++) { sRedS[w][lane][j] = po[j]; sRedQ[w][lane][j] = pq[j]; }
  }
  __syncthreads();
  if (tid < 16) {
    int o = tid, txo = o >> 2, j = o & 3;
    float s = 0.f, q = 0.f;
    #pragma unroll
    for (int ww = 0; ww < 4; ww++) { s += sRedS[ww][txo][j]; q += sRedQ[ww][txo][j]; }
    int pidx = (n * 32 + tt) * 48 + b * 16 + o;
    pSum2[pidx] = s; pSq2[pidx] = q;
  }
}

// ------------------------------------------------------------------
// Kernel 7: concat + bn + residual + relu. Block per (n, 8-t chunk).
// ------------------------------------------------------------------
__global__ __launch_bounds__(256, 8)
void k7_final(const float* __restrict__ x, const bf16* __restrict__ preB,
              const bf16* __restrict__ zbB,
              const float* __restrict__ sc1, const float* __restrict__ sh1,
              const float* __restrict__ sc2, const float* __restrict__ sh2,
              float* __restrict__ out)
{
  const int bid = blockIdx.x;            // 2048 = 32 n * 64 chunks
  const int n = bid >> 6, tc = bid & 63;
  const int t0 = tc * 8;
  for (int e = threadIdx.x; e < 12800; e += 256) {
    int ch = e / 200, r = e - ch * 200;
    int tl = r / 25, v = r - tl * 25;
    int t = t0 + tl;
    int b = ch >> 4, o = ch & 15;
    float val;
    if (b < 3) {
      val = sc2[b * 16 + o] * (float)zbB[(((b * 32 + n) * 512 + t) * 16 + o) * 25 + v]
          + sh2[b * 16 + o];
    } else {
      int ko = 48 + o;
      val = sc1[ko] * (float)preB[((n * 512 + t) * 64 + ko) * 25 + v] + sh1[ko];
    }
    int ax = (n * 64 + ch) * 12800 + t * 25 + v;
    out[ax] = fmaxf(val + x[ax], 0.f);
  }
}

// ------------------------------------------------------------------
extern "C" void kernel_launch(void* const* d_in, const int* in_sizes, int n_in,
                              void* d_out, int out_size, void* d_ws, size_t ws_size,
                              hipStream_t stream)
{
  const float* x       = (const float*)d_in[0];
  const float* topo    = (const float*)d_in[1];
  const float* ln_g    = (const float*)d_in[2];
  const float* ln_b    = (const float*)d_in[3];
  const float* qk_w    = (const float*)d_in[4];
  const float* qk_b    = (const float*)d_in[5];
  const float* convd_w = (const float*)d_in[6];
  const float* convd_b = (const float*)d_in[7];
  const float* sagc_g  = (const float*)d_in[8];
  const float* sagc_b  = (const float*)d_in[9];
  const float* w1      = (const float*)d_in[10];
  const float* b1      = (const float*)d_in[11];
  const float* bn1_g   = (const float*)d_in[12];
  const float* bn1_b   = (const float*)d_in[13];
  const float* w2      = (const float*)d_in[14];
  const float* b2      = (const float*)d_in[15];
  const float* bn2_g   = (const float*)d_in[16];
  const float* bn2_b   = (const float*)d_in[17];
  float* out = (float*)d_out;
  float* ws  = (float*)d_ws;

  bf16*  preB  = (bf16*)ws;                    // 26,214,400 bf16
  bf16*  zbB   = (bf16*)(ws + 13107200);       // 19,660,800 bf16
  float* pSum1 = ws + 22937600;                // 1,048,576
  float* pSq1  = ws + 23986176;                // 1,048,576
  float* pSum2 = ws + 25034752;                // 49,152
  float* pSq2  = ws + 25083904;                // 49,152
  float* scS   = ws + 25133056;  float* shS = scS + 64;
  float* sc1   = scS + 128;      float* sh1 = scS + 192;
  float* sc2   = scS + 256;      float* sh2 = scS + 304;
  bf16*  qkB   = (bf16*)(ws + 25133440);       // 6144 bf16
  bf16*  convB = (bf16*)(ws + 25136512);       // 12288 bf16
  bf16*  w1B   = (bf16*)(ws + 25142656);       // 8192 bf16
  float* oS1   = ws + 25146752;                // 16384
  float* oQ1   = ws + 25163136;                // 16384
  bf16*  saB   = (bf16*)d_out;                 // d_out doubles as sa scratch

  const float invN = 1.f / 409600.f;   // N*T*V

  kprepack<<<10, 256, 0, stream>>>(qk_w, convd_w, w1, qkB, convB, w1B);
  k1_sa_sagc<<<dim3(64, 32), 256, 0, stream>>>(x, topo, ln_g, ln_b, qk_b,
                                               qkB, convB, convd_b, saB, pSum1, pSq1);
  kpart<<<256, 256, 0, stream>>>(pSum1, pSq1, oS1, oQ1);
  kreduce<<<64, 256, 0, stream>>>(oS1, oQ1, 256, 64, invN, sagc_g, sagc_b, scS, shS);
  k3_ygc_pre<<<dim3(64, 32), 256, 0, stream>>>(x, saB, scS, shS, w1B, b1,
                                               preB, pSum1, pSq1);
  kpart<<<256, 256, 0, stream>>>(pSum1, pSq1, oS1, oQ1);
  kreduce<<<64, 256, 0, stream>>>(oS1, oQ1, 256, 64, invN, bn1_g, bn1_b, sc1, sh1);
  k5_tcn_branch<<<dim3(32, 3, 32), 256, 0, stream>>>(preB, sc1, sh1, w2, b2,
                                                     zbB, pSum2, pSq2);
  kreduce<<<48, 256, 0, stream>>>(pSum2, pSq2, 1024, 48, invN, bn2_g, bn2_b, sc2, sh2);
  k7_final<<<2048, 256, 0, stream>>>(x, preB, zbB, sc1, sh1, sc2, sh2, out);
}

// Round 12
// 782.382 us; speedup vs baseline: 1.0014x; 1.0014x over previous
//
#include <hip/hip_runtime.h>

// EncodingBlock — Round 11: multi-t blocks for k1 and k3 (phase math = round-10
// verbatim). One block = (n, 8 consecutive t) looping over the same LDS:
//  * kills dispatch-batch quantization (k1: 9.14 batches -> 1.14; k3: 8 -> 1)
//  * x (k1) / saB+x (k3) for t+1 prefetched into registers during t's compute
//  * k1: ln_g/ln_b in registers (old LDS slot was overlay-clobbered per t)
//  * extra end-of-t barrier protects featT/sPart (k1) rewrite vs P5/P6 reads
// k5/k7/kpart/kreduce/kprepack unchanged from round-10 (measured best).

#define EPS 1e-5f

typedef __bf16 bf16;
typedef __bf16 bf16x8 __attribute__((ext_vector_type(8)));
typedef float f32x4 __attribute__((ext_vector_type(4)));

// ------------------------------------------------------------------
// Prepack weights to MFMA B-fragments.
// ------------------------------------------------------------------
__global__ void kprepack(const float* __restrict__ qk_w, const float* __restrict__ convd_w,
                         const float* __restrict__ w1g,
                         bf16* __restrict__ qkB, bf16* __restrict__ convB, bf16* __restrict__ w1B)
{
  int gid = blockIdx.x * 256 + threadIdx.x;
  if (gid < 384) {                       // qk: (nt,ks,lane) 3*2*64, hi/lo
    int lane = gid & 63, f = gid >> 6;
    int nt = f >> 1, ks = f & 1;
    int row = nt * 16 + (lane & 15);
    int col = ks * 32 + ((lane >> 4) * 8);
    const float* src = &qk_w[row * 64 + col];
    bf16* dh = &qkB[(f * 64 + lane) * 8];
    bf16* dl = dh + 3072;
    #pragma unroll
    for (int j = 0; j < 8; j++) {
      float w = src[j];
      bf16 h = (bf16)w;
      dh[j] = h;
      dl[j] = (bf16)(w - (float)h);
    }
  } else if (gid < 1920) {               // convd: (nt,ks,lane) 4*6*64
    int g = gid - 384;
    int lane = g & 63, f = g >> 6;
    int nt = f / 6, ks = f - nt * 6;
    int k0 = ks * 32 + ((lane >> 4) * 8);
    int h = k0 >> 6, c = k0 & 63;
    int o = nt * 16 + (lane & 15);
    const float* src = &convd_w[(h * 64 + o) * 64 + c];
    bf16* d = &convB[(f * 64 + lane) * 8];
    #pragma unroll
    for (int j = 0; j < 8; j++) d[j] = (bf16)src[j];
  } else if (gid < 2432) {               // w1: (nt,ks,lane) 4*2*64, hi/lo
    int g = gid - 1920;
    int lane = g & 63, f = g >> 6;
    int nt = f >> 1, ks = f & 1;
    int ko = nt * 16 + (lane & 15);
    int c0 = ks * 32 + ((lane >> 4) * 8);
    const float* src = &w1g[ko * 64 + c0];
    bf16* dh = &w1B[(f * 64 + lane) * 8];
    bf16* dl = dh + 4096;
    #pragma unroll
    for (int j = 0; j < 8; j++) {
      float w = src[j];
      bf16 h = (bf16)w;
      dh[j] = h;
      dl[j] = (bf16)(w - (float)h);
    }
  }
}

// ------------------------------------------------------------------
// Kernel 1: fused SelfAttention + SA_GC (pre-BN). LDS 21.5 KB -> 7/CU.
// Multi-t: block = (tc, n), loops t = tc*8 .. tc*8+7 with x prefetch.
// ------------------------------------------------------------------
__global__ __launch_bounds__(256, 7)
void k1_sa_sagc(const float* __restrict__ x,
                const float* __restrict__ topo,
                const float* __restrict__ ln_g, const float* __restrict__ ln_b,
                const float* __restrict__ qk_b,
                const bf16* __restrict__ qkB, const bf16* __restrict__ convB,
                const float* __restrict__ convd_b,
                bf16* __restrict__ saB, float* __restrict__ pSum, float* __restrict__ pSq)
{
  const int tc = blockIdx.x, n = blockIdx.y, tid = threadIdx.x;
  const int lane = tid & 63, wave = tid >> 6;
  const int rr = lane & 15, co = (lane >> 4) * 8, rq = (lane >> 4) * 4;

  __shared__ __align__(16) float smem[5512];
  bf16*  featT  = (bf16*)smem;               // [64][40] bf16     [0,1280)
  float* yF     = smem + 1280;               // [25][69] f32      [1280,3005)  slot B
  bf16*  sAttn  = (bf16*)(smem + 1280);      // [75][40] bf16     overlay of yF (P4-P5)
  float* sPartS = smem + 3008;               // [25*4]            slot C
  float* sPartQ = smem + 3208;
  float* sQK    = smem + 3008;               // [25][56] f32      overlay (P3-P4)
  bf16*  zL     = (bf16*)(smem + 3008);      // [25][200] bf16    overlay (P5-P6)

  const int v = tid & 31, cb = tid >> 5;

  // LN gamma/beta in registers (thread owns channels cb+8k)
  float lng[8], lnb[8];
  #pragma unroll
  for (int k = 0; k < 8; k++) { lng[k] = ln_g[cb + 8 * k]; lnb[k] = ln_b[cb + 8 * k]; }

  // initial x load (t = tc*8)
  float xv[8];
  {
    const float* xp = &x[((n * 64 + cb) * 512 + tc * 8) * 25 + (v < 25 ? v : 0)];
    #pragma unroll
    for (int k = 0; k < 8; k++) xv[k] = (v < 25) ? xp[k * 102400] : 0.f;  // 102400 = 8*512*25
  }

  #pragma unroll 1
  for (int tl = 0; tl < 8; tl++) {
    const int t = tc * 8 + tl;
    const int blk = n * 512 + t;

    // P1: featT bf16 writes + LN partials (from registers)
    {
      float s = 0.f, q = 0.f;
      #pragma unroll
      for (int k = 0; k < 8; k++) {
        float f = xv[k];
        featT[(cb + 8 * k) * 40 + v] = (bf16)f;   // v>=25 lanes write the zero pad
        s += f; q += f * f;
      }
      s += __shfl_xor(s, 32); q += __shfl_xor(q, 32);
      if (lane < 32 && v < 25) { sPartS[v * 4 + wave] = s; sPartQ[v * 4 + wave] = q; }
    }
    // prefetch x for t+1 (overlaps P2..P6 compute)
    float xn[8];
    if (tl < 7) {
      const float* xp = &x[((n * 64 + cb) * 512 + t + 1) * 25 + (v < 25 ? v : 0)];
      #pragma unroll
      for (int k = 0; k < 8; k++) xn[k] = (v < 25) ? xp[k * 102400] : 0.f;
    }
    __syncthreads();

    // P2: finalize LN stats (redundant per thread) + y -> yF f32 (conflict-free)
    if (v < 25) {
      float S = sPartS[v * 4] + sPartS[v * 4 + 1] + sPartS[v * 4 + 2] + sPartS[v * 4 + 3];
      float Q = sPartQ[v * 4] + sPartQ[v * 4 + 1] + sPartQ[v * 4 + 2] + sPartQ[v * 4 + 3];
      float mu = S * (1.f / 64.f);
      float rstd = rsqrtf(Q * (1.f / 64.f) - mu * mu + EPS);
      #pragma unroll
      for (int k = 0; k < 8; k++) {
        int c = cb + 8 * k;
        yF[v * 69 + c] = (xv[k] - mu) * rstd * lng[k] + lnb[k];
      }
    }
    __syncthreads();

    // P3: QK projection via MFMA; hi/lo split computed in-register from yF.
    {
      const int mt = wave & 1;
      const int r0 = mt * 16 + rr;               // rows >=25 read junk -> discarded C rows
      bf16x8 Ah[2], Al[2];
      #pragma unroll
      for (int ks = 0; ks < 2; ks++) {
        const float* yp = &yF[r0 * 69 + ks * 32 + co];
        #pragma unroll
        for (int j = 0; j < 8; j++) {
          float yv = yp[j];
          bf16 h = (bf16)yv;
          Ah[ks][j] = h;
          Al[ks][j] = (bf16)(yv - (float)h);
        }
      }
      #pragma unroll
      for (int q = 0; q < 2; q++) {
        if (wave >= 2 && q > 0) break;
        int nt = (wave < 2) ? (q * 2) : 1;
        float qb = qk_b[nt * 16 + rr];
        f32x4 acc = {qb, qb, qb, qb};
        #pragma unroll
        for (int ks = 0; ks < 2; ks++) {
          bf16x8 Bh = *(const bf16x8*)&qkB[((nt * 2 + ks) * 64 + lane) * 8];
          bf16x8 Bl = *(const bf16x8*)&qkB[3072 + ((nt * 2 + ks) * 64 + lane) * 8];
          acc = __builtin_amdgcn_mfma_f32_16x16x32_bf16(Ah[ks], Bh, acc, 0, 0, 0);
          acc = __builtin_amdgcn_mfma_f32_16x16x32_bf16(Ah[ks], Bl, acc, 0, 0, 0);
          acc = __builtin_amdgcn_mfma_f32_16x16x32_bf16(Al[ks], Bh, acc, 0, 0, 0);
        }
        #pragma unroll
        for (int r = 0; r < 4; r++) {
          int i = mt * 16 + rq + r;
          if (i < 25) sQK[i * 56 + nt * 16 + rr] = acc[r];
        }
      }
    }
    __syncthreads();

    // P4: dots + softmax + *topo -> sAttn bf16 [75][40]; 2 threads per (h,i) row
    if (tid < 150) {
      int p = tid >> 1, half = tid & 1;
      int h = p / 25, i = p - (p / 25) * 25;
      const float* qr = &sQK[i * 56 + h * 8];
      float4 qa = *(const float4*)qr, qb4 = *(const float4*)(qr + 4);
      const int j0 = half * 13;
      const int cnt = 13 - half;
      float lgv[13];
      float lmax = -3.4e38f;
      #pragma unroll
      for (int jj = 0; jj < 13; jj++) {
        int j = j0 + jj; j = j > 24 ? 24 : j;
        const float* kr = &sQK[j * 56 + 24 + h * 8];
        float4 ka = *(const float4*)kr, kb = *(const float4*)(kr + 4);
        float d = qa.x * ka.x + qa.y * ka.y + qa.z * ka.z + qa.w * ka.w
                + qb4.x * kb.x + qb4.y * kb.y + qb4.z * kb.z + qb4.w * kb.w;
        d *= 0.35355339059327373f;
        lgv[jj] = d;
        lmax = fmaxf(lmax, d);
      }
      lmax = fmaxf(lmax, __shfl_xor(lmax, 1));
      float se = 0.f;
      #pragma unroll
      for (int jj = 0; jj < 13; jj++) {
        float e = __expf(lgv[jj] - lmax);
        lgv[jj] = e;
        if (jj < cnt) se += e;
      }
      se += __shfl_xor(se, 1);
      float inv = 1.f / se;
      bf16* ar = &sAttn[(h * 25 + i) * 40];
      #pragma unroll
      for (int jj = 0; jj < 13; jj++) {
        int j = j0 + jj;
        if (jj < cnt) ar[j] = (bf16)(lgv[jj] * inv * topo[(h * 25 + i) * 25 + j]);
      }
      if (half) {
        #pragma unroll
        for (int j = 25; j < 32; j++) ar[j] = (bf16)0.f;   // K-dim pad must be zero
      }
    }
    __syncthreads();

    // P5: z = A_h @ feat via MFMA; wave owns 16 feat-cols; zL [25][200]
    {
      const int nt = wave;
      bf16x8 Bf = *(const bf16x8*)&featT[(nt * 16 + rr) * 40 + co];
      #pragma unroll
      for (int h = 0; h < 3; h++) {
        #pragma unroll
        for (int mt = 0; mt < 2; mt++) {
          bf16x8 Af = *(const bf16x8*)&sAttn[(h * 25 + mt * 16 + rr) * 40 + co];
          f32x4 az = {0.f, 0.f, 0.f, 0.f};
          az = __builtin_amdgcn_mfma_f32_16x16x32_bf16(Af, Bf, az, 0, 0, 0);
          #pragma unroll
          for (int r = 0; r < 4; r++) {
            int i = mt * 16 + rq + r;
            if (i < 25) zL[i * 200 + h * 64 + nt * 16 + rr] = (bf16)az[r];
          }
        }
      }
    }
    __syncthreads();

    // P6: sa = z @ Wcat via MFMA; direct global store + shfl BN partials
    {
      const int nt = wave;
      int o = nt * 16 + rr;
      float cb2 = convd_b[o] + convd_b[64 + o] + convd_b[128 + o];
      float po = 0.f, pq = 0.f;
      #pragma unroll
      for (int mt = 0; mt < 2; mt++) {
        int zr = mt * 16 + rr;
        zr = (zr < 25) ? zr : 0;                 // clamp: stay inside zL allocation
        f32x4 acc = {cb2, cb2, cb2, cb2};
        #pragma unroll
        for (int ks = 0; ks < 6; ks++) {
          bf16x8 Az = *(const bf16x8*)&zL[zr * 200 + ks * 32 + co];
          bf16x8 Bw = *(const bf16x8*)&convB[((nt * 6 + ks) * 64 + lane) * 8];
          acc = __builtin_amdgcn_mfma_f32_16x16x32_bf16(Az, Bw, acc, 0, 0, 0);
        }
        #pragma unroll
        for (int r = 0; r < 4; r++) {
          int i = mt * 16 + rq + r;
          if (i < 25) {
            float val = acc[r];
            saB[blk * 1600 + o * 25 + i] = (bf16)val;
            po += val; pq += val * val;
          }
        }
      }
      po += __shfl_xor(po, 16); pq += __shfl_xor(pq, 16);
      po += __shfl_xor(po, 32); pq += __shfl_xor(pq, 32);
      if (lane < 16) {
        pSum[blk * 64 + o] = po;
        pSq [blk * 64 + o] = pq;
      }
    }
    __syncthreads();   // protect featT/sPart (overlays zL head) rewrite next t

    if (tl < 7) {
      #pragma unroll
      for (int k = 0; k < 8; k++) xv[k] = xn[k];
    }
  }
}

// ------------------------------------------------------------------
// kpart: coalesced first-level reduce of [16384][64] partials -> [256][64]
// ------------------------------------------------------------------
__global__ __launch_bounds__(256, 8)
void kpart(const float* __restrict__ pS, const float* __restrict__ pQ,
           float* __restrict__ oS, float* __restrict__ oQ)
{
  const int g = blockIdx.x, tid = threadIdx.x;
  const int c = tid & 63, r = tid >> 6;
  float s = 0.f, q = 0.f;
  for (int i = 0; i < 16; i++) {
    int b = g * 64 + r * 16 + i;
    s += pS[b * 64 + c]; q += pQ[b * 64 + c];
  }
  __shared__ float ls[4][64], lq[4][64];
  ls[r][c] = s; lq[r][c] = q;
  __syncthreads();
  if (tid < 64) {
    oS[g * 64 + tid] = ls[0][tid] + ls[1][tid] + ls[2][tid] + ls[3][tid];
    oQ[g * 64 + tid] = lq[0][tid] + lq[1][tid] + lq[2][tid] + lq[3][tid];
  }
}

// ------------------------------------------------------------------
// BN-stat reduce: one block per channel; partials layout [part][C]
// ------------------------------------------------------------------
__global__ __launch_bounds__(256, 4)
void kreduce(const float* __restrict__ pS, const float* __restrict__ pQ,
             int npart, int C, float invN,
             const float* __restrict__ g, const float* __restrict__ bta,
             float* __restrict__ sc, float* __restrict__ sh)
{
  int c = blockIdx.x, tid = threadIdx.x;
  float s = 0.f, q = 0.f;
  for (int i = tid; i < npart; i += 256) { s += pS[i * C + c]; q += pQ[i * C + c]; }
  #pragma unroll
  for (int m = 1; m < 64; m <<= 1) { s += __shfl_xor(s, m); q += __shfl_xor(q, m); }
  __shared__ float rs[4], rq[4];
  int w = tid >> 6;
  if ((tid & 63) == 0) { rs[w] = s; rq[w] = q; }
  __syncthreads();
  if (tid == 0) {
    float S = rs[0] + rs[1] + rs[2] + rs[3];
    float Q = rq[0] + rq[1] + rq[2] + rq[3];
    float mu = S * invN, var = Q * invN - mu * mu;
    float r = rsqrtf(var + EPS);
    sc[c] = g[c] * r;
    sh[c] = bta[c] - mu * g[c] * r;
  }
}

// ------------------------------------------------------------------
// Kernel 3: y_gc = relu(bn(sa)+x); pre = y_gc @ W1 + b1 via MFMA (hi/lo)
// Multi-t: block = (tc, n), loops 8 t's; saB/x prefetched into registers.
// ------------------------------------------------------------------
__global__ __launch_bounds__(256, 8)
void k3_ygc_pre(const float* __restrict__ x, const bf16* __restrict__ saB,
                const float* __restrict__ scS, const float* __restrict__ shS,
                const bf16* __restrict__ w1B, const float* __restrict__ b1,
                bf16* __restrict__ preB, float* __restrict__ pSum, float* __restrict__ pSq)
{
  const int tc = blockIdx.x, n = blockIdx.y, tid = threadIdx.x;
  const int lane = tid & 63, wave = tid >> 6;
  const int rr = lane & 15, co = (lane >> 4) * 8, rq = (lane >> 4) * 4;

  __shared__ __align__(16) float smem[3656];
  bf16*  yH   = (bf16*)smem;             // [25][72] bf16 -> [0, 900)
  bf16*  yL   = (bf16*)(smem + 900);     // [900, 1800)
  float* sPre = smem + 1800;             // [64][29] [1800, 3656)

  const int lin = (tid < 200) ? tid * 8 : 0;
  const int c0 = lin / 25, v0 = lin - c0 * 25;

  // initial prefetch (t = tc*8)
  bf16x8 s8 = {};
  float x8[8];
  if (tid < 200) {
    int blk0 = n * 512 + tc * 8;
    s8 = *(const bf16x8*)&saB[blk0 * 1600 + lin];
    int c = c0, v = v0;
    #pragma unroll
    for (int e = 0; e < 8; e++) {
      x8[e] = x[((n * 64 + c) * 512 + tc * 8) * 25 + v];
      if (++v == 25) { v = 0; c++; }
    }
  }

  #pragma unroll 1
  for (int tl = 0; tl < 8; tl++) {
    const int t = tc * 8 + tl;
    const int blk = n * 512 + t;

    // P1: yH/yL from registers
    if (tid < 200) {
      int c = c0, v = v0;
      #pragma unroll
      for (int e = 0; e < 8; e++) {
        float val = scS[c] * (float)s8[e] + shS[c] + x8[e];
        val = fmaxf(val, 0.f);
        bf16 h = (bf16)val;
        yH[v * 72 + c] = h;
        yL[v * 72 + c] = (bf16)(val - (float)h);
        if (++v == 25) { v = 0; c++; }
      }
    }
    // prefetch t+1 (overlaps MFMA phase)
    bf16x8 s8n = {};
    float x8n[8];
    if (tl < 7 && tid < 200) {
      s8n = *(const bf16x8*)&saB[(blk + 1) * 1600 + lin];
      int c = c0, v = v0;
      #pragma unroll
      for (int e = 0; e < 8; e++) {
        x8n[e] = x[((n * 64 + c) * 512 + t + 1) * 25 + v];
        if (++v == 25) { v = 0; c++; }
      }
    }
    __syncthreads();

    // P2: MFMA (hi/lo)
    {
      const int nt = wave;  // output cols nt*16..+15
      bf16x8 Ah[2][2], Al[2][2];
      #pragma unroll
      for (int mt = 0; mt < 2; mt++) {
        int r0 = mt * 16 + rr;               // rows >=25 read junk -> discarded
        #pragma unroll
        for (int ks = 0; ks < 2; ks++) {
          Ah[mt][ks] = *(const bf16x8*)&yH[r0 * 72 + ks * 32 + co];
          Al[mt][ks] = *(const bf16x8*)&yL[r0 * 72 + ks * 32 + co];
        }
      }
      float bb = b1[nt * 16 + rr];
      #pragma unroll
      for (int mt = 0; mt < 2; mt++) {
        f32x4 acc = {bb, bb, bb, bb};
        #pragma unroll
        for (int ks = 0; ks < 2; ks++) {
          bf16x8 Bh = *(const bf16x8*)&w1B[((nt * 2 + ks) * 64 + lane) * 8];
          bf16x8 Bl = *(const bf16x8*)&w1B[4096 + ((nt * 2 + ks) * 64 + lane) * 8];
          acc = __builtin_amdgcn_mfma_f32_16x16x32_bf16(Ah[mt][ks], Bh, acc, 0, 0, 0);
          acc = __builtin_amdgcn_mfma_f32_16x16x32_bf16(Ah[mt][ks], Bl, acc, 0, 0, 0);
          acc = __builtin_amdgcn_mfma_f32_16x16x32_bf16(Al[mt][ks], Bh, acc, 0, 0, 0);
        }
        #pragma unroll
        for (int r = 0; r < 4; r++) {
          int i = mt * 16 + rq + r;
          if (i < 25) sPre[(nt * 16 + rr) * 29 + i] = acc[r];
        }
      }
    }
    __syncthreads();

    // P3: store preB + BN partials
    if (tid < 200) {
      bf16x8 p8;
      int ko = c0, v = v0;
      #pragma unroll
      for (int e = 0; e < 8; e++) {
        p8[e] = (bf16)sPre[ko * 29 + v];
        if (++v == 25) { v = 0; ko++; }
      }
      *(bf16x8*)&preB[blk * 1600 + lin] = p8;
    }
    if (tid < 64) {
      float s = 0.f, q = 0.f;
      #pragma unroll
      for (int i = 0; i < 25; i++) { float vv = sPre[tid * 29 + i]; s += vv; q += vv * vv; }
      pSum[blk * 64 + tid] = s;
      pSq [blk * 64 + tid] = q;
    }
    // no extra barrier needed: next P1 writes yH/yL (all waves passed post-P2
    // barrier => P2 reads done); P2(t+1) is fenced from P3(t) by post-P1 barrier.

    if (tl < 7 && tid < 200) {
      s8 = s8n;
      #pragma unroll
      for (int e = 0; e < 8; e++) x8[e] = x8n[e];
    }
  }
}

// ------------------------------------------------------------------
// Kernel 5: TCN branches; preB [n][t][ch][v], zbB [b][n][t][o][v]
// Single-stage 16-ch staging (44KB LDS, 3 blocks/CU) — measured best.
// ------------------------------------------------------------------
template<int D>
__device__ __forceinline__ void conv5(const float* __restrict__ sIn, const float* __restrict__ sW,
                                      float4 bias, int o4, int v, int tb, float acc[8][4])
{
  #pragma unroll
  for (int s = 0; s < 8; s++) {
    acc[s][0] = bias.x; acc[s][1] = bias.y; acc[s][2] = bias.z; acc[s][3] = bias.w;
  }
  const int NW = 8 + 4 * D;
  for (int ic = 0; ic < 16; ic++) {
    float4 wk[5];
    #pragma unroll
    for (int kt = 0; kt < 5; kt++) wk[kt] = *(const float4*)&sW[(ic * 5 + kt) * 16 + o4];
    float xw[8 + 4 * D];
    #pragma unroll
    for (int w = 0; w < NW; w++) xw[w] = sIn[(ic * 24 + (tb - 2 * D + w + 4)) * 25 + v];
    #pragma unroll
    for (int s = 0; s < 8; s++)
      #pragma unroll
      for (int kt = 0; kt < 5; kt++) {
        float xv = xw[s + kt * D];
        acc[s][0] += xv * wk[kt].x; acc[s][1] += xv * wk[kt].y;
        acc[s][2] += xv * wk[kt].z; acc[s][3] += xv * wk[kt].w;
      }
  }
}

__global__ __launch_bounds__(256, 3)
void k5_tcn_branch(const bf16* __restrict__ preB,
                   const float* __restrict__ sc1, const float* __restrict__ sh1,
                   const float* __restrict__ w2, const float* __restrict__ b2,
                   bf16* __restrict__ zbB, float* __restrict__ pSum2, float* __restrict__ pSq2)
{
  const int tt = blockIdx.x, b = blockIdx.y, n = blockIdx.z;
  const int tid = threadIdx.x, t0 = tt * 16;
  __shared__ __align__(16) float sIn[16 * 24 * 25];
  __shared__ __align__(16) float sW[16 * 5 * 16];
  __shared__ float sRedS[4][4][4], sRedQ[4][4][4];

  for (int idx = tid; idx < 1200; idx += 256) {
    int r = idx / 50, k8 = idx - r * 50;
    int gt = t0 - 4 + r;
    int lin = k8 * 8;
    if (gt >= 0 && gt < 512) {
      bf16x8 p8 = *(const bf16x8*)&preB[((n * 512 + gt) * 64 + b * 16) * 25 + lin];
      #pragma unroll
      for (int e = 0; e < 8; e++) {
        int q = lin + e, ic = q / 25, v = q - ic * 25;
        int ch = b * 16 + ic;
        sIn[(ic * 24 + r) * 25 + v] = fmaxf(sc1[ch] * (float)p8[e] + sh1[ch], 0.f);
      }
    } else {
      #pragma unroll
      for (int e = 0; e < 8; e++) {
        int q = lin + e, ic = q / 25, v = q - ic * 25;
        sIn[(ic * 24 + r) * 25 + v] = 0.f;
      }
    }
  }
  if (b < 2)
    for (int idx = tid; idx < 1280; idx += 256) {
      int o = idx / 80, rem = idx - o * 80;
      int ic = rem / 5, kt = rem - ic * 5;
      sW[(ic * 5 + kt) * 16 + o] = w2[((b * 16 + o) * 16 + ic) * 5 + kt];
    }
  __syncthreads();

  float po[4] = {0.f, 0.f, 0.f, 0.f}, pq[4] = {0.f, 0.f, 0.f, 0.f};
  if (tid < 200) {
    int tx = tid & 3, o4 = tx * 4;
    int g = tid >> 2;
    int v = g % 25, th = g / 25;
    int tb = th * 8;
    float acc[8][4];
    if (b == 0)      conv5<1>(sIn, sW, *(const float4*)&b2[o4],      o4, v, tb, acc);
    else if (b == 1) conv5<2>(sIn, sW, *(const float4*)&b2[16 + o4], o4, v, tb, acc);
    else {
      #pragma unroll
      for (int s = 0; s < 8; s++)
        #pragma unroll
        for (int j = 0; j < 4; j++) {
          int o = o4 + j, r = tb + s + 4;
          float a = sIn[(o * 24 + r - 1) * 25 + v];
          float m = sIn[(o * 24 + r    ) * 25 + v];
          float c = sIn[(o * 24 + r + 1) * 25 + v];
          acc[s][j] = fmaxf(fmaxf(a, m), c);
        }
    }
    #pragma unroll
    for (int s = 0; s < 8; s++) {
      int gt = t0 + tb + s;
      #pragma unroll
      for (int j = 0; j < 4; j++) {
        float val = acc[s][j];
        zbB[(((b * 32 + n) * 512 + gt) * 16 + (o4 + j)) * 25 + v] = (bf16)val;
        po[j] += val; pq[j] += val * val;
      }
    }
  }
  #pragma unroll
  for (int m = 4; m < 64; m <<= 1) {
    #pragma unroll
    for (int j = 0; j < 4; j++) { po[j] += __shfl_xor(po[j], m); pq[j] += __shfl_xor(pq[j], m); }
  }
  int lane = tid & 63, w = tid >> 6;
  if (lane < 4) {
    #pragma unroll
    for (int j = 0; j < 4; j++) { sRedS[w][lane][j] = po[j]; sRedQ[w][lane][j] = pq[j]; }
  }
  __syncthreads();
  if (tid < 16) {
    int o = tid, txo = o >> 2, j = o & 3;
    float s = 0.f, q = 0.f;
    #pragma unroll
    for (int ww = 0; ww < 4; ww++) { s += sRedS[ww][txo][j]; q += sRedQ[ww][txo][j]; }
    int pidx = (n * 32 + tt) * 48 + b * 16 + o;
    pSum2[pidx] = s; pSq2[pidx] = q;
  }
}

// ------------------------------------------------------------------
// Kernel 7: concat + bn + residual + relu. Block per (n, 8-t chunk).
// ------------------------------------------------------------------
__global__ __launch_bounds__(256, 8)
void k7_final(const float* __restrict__ x, const bf16* __restrict__ preB,
              const bf16* __restrict__ zbB,
              const float* __restrict__ sc1, const float* __restrict__ sh1,
              const float* __restrict__ sc2, const float* __restrict__ sh2,
              float* __restrict__ out)
{
  const int bid = blockIdx.x;            // 2048 = 32 n * 64 chunks
  const int n = bid >> 6, tc = bid & 63;
  const int t0 = tc * 8;
  for (int e = threadIdx.x; e < 12800; e += 256) {
    int ch = e / 200, r = e - ch * 200;
    int tl = r / 25, v = r - tl * 25;
    int t = t0 + tl;
    int b = ch >> 4, o = ch & 15;
    float val;
    if (b < 3) {
      val = sc2[b * 16 + o] * (float)zbB[(((b * 32 + n) * 512 + t) * 16 + o) * 25 + v]
          + sh2[b * 16 + o];
    } else {
      int ko = 48 + o;
      val = sc1[ko] * (float)preB[((n * 512 + t) * 64 + ko) * 25 + v] + sh1[ko];
    }
    int ax = (n * 64 + ch) * 12800 + t * 25 + v;
    out[ax] = fmaxf(val + x[ax], 0.f);
  }
}

// ------------------------------------------------------------------
extern "C" void kernel_launch(void* const* d_in, const int* in_sizes, int n_in,
                              void* d_out, int out_size, void* d_ws, size_t ws_size,
                              hipStream_t stream)
{
  const float* x       = (const float*)d_in[0];
  const float* topo    = (const float*)d_in[1];
  const float* ln_g    = (const float*)d_in[2];
  const float* ln_b    = (const float*)d_in[3];
  const float* qk_w    = (const float*)d_in[4];
  const float* qk_b    = (const float*)d_in[5];
  const float* convd_w = (const float*)d_in[6];
  const float* convd_b = (const float*)d_in[7];
  const float* sagc_g  = (const float*)d_in[8];
  const float* sagc_b  = (const float*)d_in[9];
  const float* w1      = (const float*)d_in[10];
  const float* b1      = (const float*)d_in[11];
  const float* bn1_g   = (const float*)d_in[12];
  const float* bn1_b   = (const float*)d_in[13];
  const float* w2      = (const float*)d_in[14];
  const float* b2      = (const float*)d_in[15];
  const float* bn2_g   = (const float*)d_in[16];
  const float* bn2_b   = (const float*)d_in[17];
  float* out = (float*)d_out;
  float* ws  = (float*)d_ws;

  bf16*  preB  = (bf16*)ws;                    // 26,214,400 bf16
  bf16*  zbB   = (bf16*)(ws + 13107200);       // 19,660,800 bf16
  float* pSum1 = ws + 22937600;                // 1,048,576
  float* pSq1  = ws + 23986176;                // 1,048,576
  float* pSum2 = ws + 25034752;                // 49,152
  float* pSq2  = ws + 25083904;                // 49,152
  float* scS   = ws + 25133056;  float* shS = scS + 64;
  float* sc1   = scS + 128;      float* sh1 = scS + 192;
  float* sc2   = scS + 256;      float* sh2 = scS + 304;
  bf16*  qkB   = (bf16*)(ws + 25133440);       // 6144 bf16
  bf16*  convB = (bf16*)(ws + 25136512);       // 12288 bf16
  bf16*  w1B   = (bf16*)(ws + 25142656);       // 8192 bf16
  float* oS1   = ws + 25146752;                // 16384
  float* oQ1   = ws + 25163136;                // 16384
  bf16*  saB   = (bf16*)d_out;                 // d_out doubles as sa scratch

  const float invN = 1.f / 409600.f;   // N*T*V

  kprepack<<<10, 256, 0, stream>>>(qk_w, convd_w, w1, qkB, convB, w1B);
  k1_sa_sagc<<<dim3(64, 32), 256, 0, stream>>>(x, topo, ln_g, ln_b, qk_b,
                                               qkB, convB, convd_b, saB, pSum1, pSq1);
  kpart<<<256, 256, 0, stream>>>(pSum1, pSq1, oS1, oQ1);
  kreduce<<<64, 256, 0, stream>>>(oS1, oQ1, 256, 64, invN, sagc_g, sagc_b, scS, shS);
  k3_ygc_pre<<<dim3(64, 32), 256, 0, stream>>>(x, saB, scS, shS, w1B, b1,
                                               preB, pSum1, pSq1);
  kpart<<<256, 256, 0, stream>>>(pSum1, pSq1, oS1, oQ1);
  kreduce<<<64, 256, 0, stream>>>(oS1, oQ1, 256, 64, invN, bn1_g, bn1_b, sc1, sh1);
  k5_tcn_branch<<<dim3(32, 3, 32), 256, 0, stream>>>(preB, sc1, sh1, w2, b2,
                                                     zbB, pSum2, pSq2);
  kreduce<<<48, 256, 0, stream>>>(pSum2, pSq2, 1024, 48, invN, bn2_g, bn2_b, sc2, sh2);
  k7_final<<<2048, 256, 0, stream>>>(x, preB, zbB, sc1, sh1, sc2, sh2, out);
}

// Round 13
// 336.628 us; speedup vs baseline: 2.3275x; 2.3242x over previous
//
#include <hip/hip_runtime.h>

// EncodingBlock — Round 13: exact revert to the round-10 build (measured
// 335.4/336.3 µs). Round-11's multi-t k1/k3 regressed 2.3x: per-t weight
// B-frag reads (36.9KB x 8t x 2048 blocks ~ 604MB) began missing L2 —
// block granularity was load-bearing for weight residency (FETCH 115->770MB,
// MfmaUtil 8.4->2.5). All structural variants beyond this build (r8 xB,
// r8/r9 two-half k5, r11 multi-t) measured as regressions; this is the
// verified local optimum.

#define EPS 1e-5f

typedef __bf16 bf16;
typedef __bf16 bf16x8 __attribute__((ext_vector_type(8)));
typedef float f32x4 __attribute__((ext_vector_type(4)));

// ------------------------------------------------------------------
// Prepack weights to MFMA B-fragments.
// ------------------------------------------------------------------
__global__ void kprepack(const float* __restrict__ qk_w, const float* __restrict__ convd_w,
                         const float* __restrict__ w1g,
                         bf16* __restrict__ qkB, bf16* __restrict__ convB, bf16* __restrict__ w1B)
{
  int gid = blockIdx.x * 256 + threadIdx.x;
  if (gid < 384) {                       // qk: (nt,ks,lane) 3*2*64, hi/lo
    int lane = gid & 63, f = gid >> 6;
    int nt = f >> 1, ks = f & 1;
    int row = nt * 16 + (lane & 15);
    int col = ks * 32 + ((lane >> 4) * 8);
    const float* src = &qk_w[row * 64 + col];
    bf16* dh = &qkB[(f * 64 + lane) * 8];
    bf16* dl = dh + 3072;
    #pragma unroll
    for (int j = 0; j < 8; j++) {
      float w = src[j];
      bf16 h = (bf16)w;
      dh[j] = h;
      dl[j] = (bf16)(w - (float)h);
    }
  } else if (gid < 1920) {               // convd: (nt,ks,lane) 4*6*64
    int g = gid - 384;
    int lane = g & 63, f = g >> 6;
    int nt = f / 6, ks = f - nt * 6;
    int k0 = ks * 32 + ((lane >> 4) * 8);
    int h = k0 >> 6, c = k0 & 63;
    int o = nt * 16 + (lane & 15);
    const float* src = &convd_w[(h * 64 + o) * 64 + c];
    bf16* d = &convB[(f * 64 + lane) * 8];
    #pragma unroll
    for (int j = 0; j < 8; j++) d[j] = (bf16)src[j];
  } else if (gid < 2432) {               // w1: (nt,ks,lane) 4*2*64, hi/lo
    int g = gid - 1920;
    int lane = g & 63, f = g >> 6;
    int nt = f >> 1, ks = f & 1;
    int ko = nt * 16 + (lane & 15);
    int c0 = ks * 32 + ((lane >> 4) * 8);
    const float* src = &w1g[ko * 64 + c0];
    bf16* dh = &w1B[(f * 64 + lane) * 8];
    bf16* dl = dh + 4096;
    #pragma unroll
    for (int j = 0; j < 8; j++) {
      float w = src[j];
      bf16 h = (bf16)w;
      dh[j] = h;
      dl[j] = (bf16)(w - (float)h);
    }
  }
}

// ------------------------------------------------------------------
// Kernel 1: fused SelfAttention + SA_GC (pre-BN). LDS 21.5 KB -> 7/CU.
// ------------------------------------------------------------------
__global__ __launch_bounds__(256, 7)
void k1_sa_sagc(const float* __restrict__ x,
                const float* __restrict__ topo,
                const float* __restrict__ ln_g, const float* __restrict__ ln_b,
                const float* __restrict__ qk_b,
                const bf16* __restrict__ qkB, const bf16* __restrict__ convB,
                const float* __restrict__ convd_b,
                bf16* __restrict__ saB, float* __restrict__ pSum, float* __restrict__ pSq)
{
  const int t = blockIdx.x, n = blockIdx.y, tid = threadIdx.x;
  const int blk = n * 512 + t;
  const int lane = tid & 63, wave = tid >> 6;
  const int rr = lane & 15, co = (lane >> 4) * 8, rq = (lane >> 4) * 4;

  __shared__ __align__(16) float smem[5512];
  bf16*  featT  = (bf16*)smem;               // [64][40] bf16     [0,1280)
  float* yF     = smem + 1280;               // [25][69] f32      [1280,3005)  slot B
  bf16*  sAttn  = (bf16*)(smem + 1280);      // [75][40] bf16     overlay of yF (P4-P5)
  float* sPartS = smem + 3008;               // [25*4]            slot C
  float* sPartQ = smem + 3208;
  float* sLnG   = smem + 3408;               // [64]
  float* sLnB   = smem + 3472;               // [64]
  float* sQK    = smem + 3008;               // [25][56] f32      overlay (P3-P4)
  bf16*  zL     = (bf16*)(smem + 3008);      // [25][200] bf16    overlay (P5-P6)

  // P1: load x (coalesced, kept in regs), featT bf16, LN partials
  const int v = tid & 31, cb = tid >> 5;
  float xv[8];
  {
    const float* xp = &x[((n * 64 + cb) * 512 + t) * 25 + (v < 25 ? v : 0)];
    float s = 0.f, q = 0.f;
    #pragma unroll
    for (int k = 0; k < 8; k++) {
      float f = (v < 25) ? xp[k * 102400] : 0.f;   // 102400 = 8*512*25
      xv[k] = f;
      featT[(cb + 8 * k) * 40 + v] = (bf16)f;
      s += f; q += f * f;
    }
    s += __shfl_xor(s, 32); q += __shfl_xor(q, 32);
    if (lane < 32 && v < 25) { sPartS[v * 4 + wave] = s; sPartQ[v * 4 + wave] = q; }
    if (tid < 64) { sLnG[tid] = ln_g[tid]; sLnB[tid] = ln_b[tid]; }
    if (tid < 64) {
      #pragma unroll
      for (int j = 25; j < 32; j++) featT[tid * 40 + j] = (bf16)0.f;
    }
  }
  __syncthreads();

  // P2: finalize LN stats (redundant per thread) + y -> yF f32 (conflict-free)
  if (v < 25) {
    float S = sPartS[v * 4] + sPartS[v * 4 + 1] + sPartS[v * 4 + 2] + sPartS[v * 4 + 3];
    float Q = sPartQ[v * 4] + sPartQ[v * 4 + 1] + sPartQ[v * 4 + 2] + sPartQ[v * 4 + 3];
    float mu = S * (1.f / 64.f);
    float rstd = rsqrtf(Q * (1.f / 64.f) - mu * mu + EPS);
    #pragma unroll
    for (int k = 0; k < 8; k++) {
      int c = cb + 8 * k;
      yF[v * 69 + c] = (xv[k] - mu) * rstd * sLnG[c] + sLnB[c];
    }
  }
  __syncthreads();

  // P3: QK projection via MFMA; hi/lo split computed in-register from yF.
  {
    const int mt = wave & 1;
    const int r0 = mt * 16 + rr;               // rows >=25 read junk -> discarded C rows
    bf16x8 Ah[2], Al[2];
    #pragma unroll
    for (int ks = 0; ks < 2; ks++) {
      const float* yp = &yF[r0 * 69 + ks * 32 + co];
      #pragma unroll
      for (int j = 0; j < 8; j++) {
        float yv = yp[j];
        bf16 h = (bf16)yv;
        Ah[ks][j] = h;
        Al[ks][j] = (bf16)(yv - (float)h);
      }
    }
    #pragma unroll
    for (int q = 0; q < 2; q++) {
      if (wave >= 2 && q > 0) break;
      int nt = (wave < 2) ? (q * 2) : 1;
      float qb = qk_b[nt * 16 + rr];
      f32x4 acc = {qb, qb, qb, qb};
      #pragma unroll
      for (int ks = 0; ks < 2; ks++) {
        bf16x8 Bh = *(const bf16x8*)&qkB[((nt * 2 + ks) * 64 + lane) * 8];
        bf16x8 Bl = *(const bf16x8*)&qkB[3072 + ((nt * 2 + ks) * 64 + lane) * 8];
        acc = __builtin_amdgcn_mfma_f32_16x16x32_bf16(Ah[ks], Bh, acc, 0, 0, 0);
        acc = __builtin_amdgcn_mfma_f32_16x16x32_bf16(Ah[ks], Bl, acc, 0, 0, 0);
        acc = __builtin_amdgcn_mfma_f32_16x16x32_bf16(Al[ks], Bh, acc, 0, 0, 0);
      }
      #pragma unroll
      for (int r = 0; r < 4; r++) {
        int i = mt * 16 + rq + r;
        if (i < 25) sQK[i * 56 + nt * 16 + rr] = acc[r];
      }
    }
  }
  __syncthreads();

  // P4: dots + softmax + *topo -> sAttn bf16 [75][40]; 2 threads per (h,i) row
  if (tid < 150) {
    int p = tid >> 1, half = tid & 1;
    int h = p / 25, i = p - (p / 25) * 25;
    const float* qr = &sQK[i * 56 + h * 8];
    float4 qa = *(const float4*)qr, qb4 = *(const float4*)(qr + 4);
    const int j0 = half * 13;
    const int cnt = 13 - half;
    float lgv[13];
    float lmax = -3.4e38f;
    #pragma unroll
    for (int jj = 0; jj < 13; jj++) {
      int j = j0 + jj; j = j > 24 ? 24 : j;
      const float* kr = &sQK[j * 56 + 24 + h * 8];
      float4 ka = *(const float4*)kr, kb = *(const float4*)(kr + 4);
      float d = qa.x * ka.x + qa.y * ka.y + qa.z * ka.z + qa.w * ka.w
              + qb4.x * kb.x + qb4.y * kb.y + qb4.z * kb.z + qb4.w * kb.w;
      d *= 0.35355339059327373f;
      lgv[jj] = d;
      lmax = fmaxf(lmax, d);
    }
    lmax = fmaxf(lmax, __shfl_xor(lmax, 1));
    float se = 0.f;
    #pragma unroll
    for (int jj = 0; jj < 13; jj++) {
      float e = __expf(lgv[jj] - lmax);
      lgv[jj] = e;
      if (jj < cnt) se += e;
    }
    se += __shfl_xor(se, 1);
    float inv = 1.f / se;
    bf16* ar = &sAttn[(h * 25 + i) * 40];
    #pragma unroll
    for (int jj = 0; jj < 13; jj++) {
      int j = j0 + jj;
      if (jj < cnt) ar[j] = (bf16)(lgv[jj] * inv * topo[(h * 25 + i) * 25 + j]);
    }
    if (half) {
      #pragma unroll
      for (int j = 25; j < 32; j++) ar[j] = (bf16)0.f;   // K-dim pad must be zero
    }
  }
  __syncthreads();

  // P5: z = A_h @ feat via MFMA; wave owns 16 feat-cols; zL [25][200]
  {
    const int nt = wave;
    bf16x8 Bf = *(const bf16x8*)&featT[(nt * 16 + rr) * 40 + co];
    #pragma unroll
    for (int h = 0; h < 3; h++) {
      #pragma unroll
      for (int mt = 0; mt < 2; mt++) {
        bf16x8 Af = *(const bf16x8*)&sAttn[(h * 25 + mt * 16 + rr) * 40 + co];
        f32x4 az = {0.f, 0.f, 0.f, 0.f};
        az = __builtin_amdgcn_mfma_f32_16x16x32_bf16(Af, Bf, az, 0, 0, 0);
        #pragma unroll
        for (int r = 0; r < 4; r++) {
          int i = mt * 16 + rq + r;
          if (i < 25) zL[i * 200 + h * 64 + nt * 16 + rr] = (bf16)az[r];
        }
      }
    }
  }
  __syncthreads();

  // P6: sa = z @ Wcat via MFMA; direct global store + shfl BN partials
  {
    const int nt = wave;
    int o = nt * 16 + rr;
    float cb2 = convd_b[o] + convd_b[64 + o] + convd_b[128 + o];
    float po = 0.f, pq = 0.f;
    #pragma unroll
    for (int mt = 0; mt < 2; mt++) {
      int zr = mt * 16 + rr;
      zr = (zr < 25) ? zr : 0;                 // clamp: stay inside zL allocation
      f32x4 acc = {cb2, cb2, cb2, cb2};
      #pragma unroll
      for (int ks = 0; ks < 6; ks++) {
        bf16x8 Az = *(const bf16x8*)&zL[zr * 200 + ks * 32 + co];
        bf16x8 Bw = *(const bf16x8*)&convB[((nt * 6 + ks) * 64 + lane) * 8];
        acc = __builtin_amdgcn_mfma_f32_16x16x32_bf16(Az, Bw, acc, 0, 0, 0);
      }
      #pragma unroll
      for (int r = 0; r < 4; r++) {
        int i = mt * 16 + rq + r;
        if (i < 25) {
          float val = acc[r];
          saB[blk * 1600 + o * 25 + i] = (bf16)val;
          po += val; pq += val * val;
        }
      }
    }
    po += __shfl_xor(po, 16); pq += __shfl_xor(pq, 16);
    po += __shfl_xor(po, 32); pq += __shfl_xor(pq, 32);
    if (lane < 16) {
      pSum[blk * 64 + o] = po;
      pSq [blk * 64 + o] = pq;
    }
  }
}

// ------------------------------------------------------------------
// kpart: coalesced first-level reduce of [16384][64] partials -> [256][64]
// ------------------------------------------------------------------
__global__ __launch_bounds__(256, 8)
void kpart(const float* __restrict__ pS, const float* __restrict__ pQ,
           float* __restrict__ oS, float* __restrict__ oQ)
{
  const int g = blockIdx.x, tid = threadIdx.x;
  const int c = tid & 63, r = tid >> 6;
  float s = 0.f, q = 0.f;
  for (int i = 0; i < 16; i++) {
    int b = g * 64 + r * 16 + i;
    s += pS[b * 64 + c]; q += pQ[b * 64 + c];
  }
  __shared__ float ls[4][64], lq[4][64];
  ls[r][c] = s; lq[r][c] = q;
  __syncthreads();
  if (tid < 64) {
    oS[g * 64 + tid] = ls[0][tid] + ls[1][tid] + ls[2][tid] + ls[3][tid];
    oQ[g * 64 + tid] = lq[0][tid] + lq[1][tid] + lq[2][tid] + lq[3][tid];
  }
}

// ------------------------------------------------------------------
// BN-stat reduce: one block per channel; partials layout [part][C]
// ------------------------------------------------------------------
__global__ __launch_bounds__(256, 4)
void kreduce(const float* __restrict__ pS, const float* __restrict__ pQ,
             int npart, int C, float invN,
             const float* __restrict__ g, const float* __restrict__ bta,
             float* __restrict__ sc, float* __restrict__ sh)
{
  int c = blockIdx.x, tid = threadIdx.x;
  float s = 0.f, q = 0.f;
  for (int i = tid; i < npart; i += 256) { s += pS[i * C + c]; q += pQ[i * C + c]; }
  #pragma unroll
  for (int m = 1; m < 64; m <<= 1) { s += __shfl_xor(s, m); q += __shfl_xor(q, m); }
  __shared__ float rs[4], rq[4];
  int w = tid >> 6;
  if ((tid & 63) == 0) { rs[w] = s; rq[w] = q; }
  __syncthreads();
  if (tid == 0) {
    float S = rs[0] + rs[1] + rs[2] + rs[3];
    float Q = rq[0] + rq[1] + rq[2] + rq[3];
    float mu = S * invN, var = Q * invN - mu * mu;
    float r = rsqrtf(var + EPS);
    sc[c] = g[c] * r;
    sh[c] = bta[c] - mu * g[c] * r;
  }
}

// ------------------------------------------------------------------
// Kernel 3: y_gc = relu(bn(sa)+x); pre = y_gc @ W1 + b1 via MFMA (hi/lo)
// ------------------------------------------------------------------
__global__ __launch_bounds__(256, 8)
void k3_ygc_pre(const float* __restrict__ x, const bf16* __restrict__ saB,
                const float* __restrict__ scS, const float* __restrict__ shS,
                const bf16* __restrict__ w1B, const float* __restrict__ b1,
                bf16* __restrict__ preB, float* __restrict__ pSum, float* __restrict__ pSq)
{
  const int t = blockIdx.x, n = blockIdx.y, tid = threadIdx.x;
  const int blk = n * 512 + t;
  const int lane = tid & 63, wave = tid >> 6;
  const int rr = lane & 15, co = (lane >> 4) * 8, rq = (lane >> 4) * 4;

  __shared__ __align__(16) float smem[3656];
  bf16*  yH   = (bf16*)smem;             // [25][72] bf16 -> [0, 900)
  bf16*  yL   = (bf16*)(smem + 900);     // [900, 1800)
  float* sPre = smem + 1800;             // [64][29] [1800, 3656)

  if (tid < 200) {
    int lin = tid * 8;
    int c = lin / 25, v = lin - c * 25;
    bf16x8 s8 = *(const bf16x8*)&saB[blk * 1600 + lin];
    #pragma unroll
    for (int e = 0; e < 8; e++) {
      float val = scS[c] * (float)s8[e] + shS[c] + x[((n * 64 + c) * 512 + t) * 25 + v];
      val = fmaxf(val, 0.f);
      bf16 h = (bf16)val;
      yH[v * 72 + c] = h;
      yL[v * 72 + c] = (bf16)(val - (float)h);
      if (++v == 25) { v = 0; c++; }
    }
  }
  __syncthreads();

  {
    const int nt = wave;  // output cols nt*16..+15
    bf16x8 Ah[2][2], Al[2][2];
    #pragma unroll
    for (int mt = 0; mt < 2; mt++) {
      int r0 = mt * 16 + rr;               // rows >=25 read junk -> discarded
      #pragma unroll
      for (int ks = 0; ks < 2; ks++) {
        Ah[mt][ks] = *(const bf16x8*)&yH[r0 * 72 + ks * 32 + co];
        Al[mt][ks] = *(const bf16x8*)&yL[r0 * 72 + ks * 32 + co];
      }
    }
    float bb = b1[nt * 16 + rr];
    #pragma unroll
    for (int mt = 0; mt < 2; mt++) {
      f32x4 acc = {bb, bb, bb, bb};
      #pragma unroll
      for (int ks = 0; ks < 2; ks++) {
        bf16x8 Bh = *(const bf16x8*)&w1B[((nt * 2 + ks) * 64 + lane) * 8];
        bf16x8 Bl = *(const bf16x8*)&w1B[4096 + ((nt * 2 + ks) * 64 + lane) * 8];
        acc = __builtin_amdgcn_mfma_f32_16x16x32_bf16(Ah[mt][ks], Bh, acc, 0, 0, 0);
        acc = __builtin_amdgcn_mfma_f32_16x16x32_bf16(Ah[mt][ks], Bl, acc, 0, 0, 0);
        acc = __builtin_amdgcn_mfma_f32_16x16x32_bf16(Al[mt][ks], Bh, acc, 0, 0, 0);
      }
      #pragma unroll
      for (int r = 0; r < 4; r++) {
        int i = mt * 16 + rq + r;
        if (i < 25) sPre[(nt * 16 + rr) * 29 + i] = acc[r];
      }
    }
  }
  __syncthreads();

  if (tid < 200) {
    int lin = tid * 8;
    bf16x8 p8;
    #pragma unroll
    for (int e = 0; e < 8; e++) {
      int q = lin + e, ko = q / 25, v = q - ko * 25;
      p8[e] = (bf16)sPre[ko * 29 + v];
    }
    *(bf16x8*)&preB[blk * 1600 + lin] = p8;
  }
  if (tid < 64) {
    float s = 0.f, q = 0.f;
    #pragma unroll
    for (int i = 0; i < 25; i++) { float v = sPre[tid * 29 + i]; s += v; q += v * v; }
    pSum[blk * 64 + tid] = s;
    pSq [blk * 64 + tid] = q;
  }
}

// ------------------------------------------------------------------
// Kernel 5: TCN branches; preB [n][t][ch][v], zbB [b][n][t][o][v]
// Single-stage 16-ch staging (44KB LDS, 3 blocks/CU) — measured best.
// ------------------------------------------------------------------
template<int D>
__device__ __forceinline__ void conv5(const float* __restrict__ sIn, const float* __restrict__ sW,
                                      float4 bias, int o4, int v, int tb, float acc[8][4])
{
  #pragma unroll
  for (int s = 0; s < 8; s++) {
    acc[s][0] = bias.x; acc[s][1] = bias.y; acc[s][2] = bias.z; acc[s][3] = bias.w;
  }
  const int NW = 8 + 4 * D;
  for (int ic = 0; ic < 16; ic++) {
    float4 wk[5];
    #pragma unroll
    for (int kt = 0; kt < 5; kt++) wk[kt] = *(const float4*)&sW[(ic * 5 + kt) * 16 + o4];
    float xw[8 + 4 * D];
    #pragma unroll
    for (int w = 0; w < NW; w++) xw[w] = sIn[(ic * 24 + (tb - 2 * D + w + 4)) * 25 + v];
    #pragma unroll
    for (int s = 0; s < 8; s++)
      #pragma unroll
      for (int kt = 0; kt < 5; kt++) {
        float xv = xw[s + kt * D];
        acc[s][0] += xv * wk[kt].x; acc[s][1] += xv * wk[kt].y;
        acc[s][2] += xv * wk[kt].z; acc[s][3] += xv * wk[kt].w;
      }
  }
}

__global__ __launch_bounds__(256, 3)
void k5_tcn_branch(const bf16* __restrict__ preB,
                   const float* __restrict__ sc1, const float* __restrict__ sh1,
                   const float* __restrict__ w2, const float* __restrict__ b2,
                   bf16* __restrict__ zbB, float* __restrict__ pSum2, float* __restrict__ pSq2)
{
  const int tt = blockIdx.x, b = blockIdx.y, n = blockIdx.z;
  const int tid = threadIdx.x, t0 = tt * 16;
  __shared__ __align__(16) float sIn[16 * 24 * 25];
  __shared__ __align__(16) float sW[16 * 5 * 16];
  __shared__ float sRedS[4][4][4], sRedQ[4][4][4];

  for (int idx = tid; idx < 1200; idx += 256) {
    int r = idx / 50, k8 = idx - r * 50;
    int gt = t0 - 4 + r;
    int lin = k8 * 8;
    if (gt >= 0 && gt < 512) {
      bf16x8 p8 = *(const bf16x8*)&preB[((n * 512 + gt) * 64 + b * 16) * 25 + lin];
      #pragma unroll
      for (int e = 0; e < 8; e++) {
        int q = lin + e, ic = q / 25, v = q - ic * 25;
        int ch = b * 16 + ic;
        sIn[(ic * 24 + r) * 25 + v] = fmaxf(sc1[ch] * (float)p8[e] + sh1[ch], 0.f);
      }
    } else {
      #pragma unroll
      for (int e = 0; e < 8; e++) {
        int q = lin + e, ic = q / 25, v = q - ic * 25;
        sIn[(ic * 24 + r) * 25 + v] = 0.f;
      }
    }
  }
  if (b < 2)
    for (int idx = tid; idx < 1280; idx += 256) {
      int o = idx / 80, rem = idx - o * 80;
      int ic = rem / 5, kt = rem - ic * 5;
      sW[(ic * 5 + kt) * 16 + o] = w2[((b * 16 + o) * 16 + ic) * 5 + kt];
    }
  __syncthreads();

  float po[4] = {0.f, 0.f, 0.f, 0.f}, pq[4] = {0.f, 0.f, 0.f, 0.f};
  if (tid < 200) {
    int tx = tid & 3, o4 = tx * 4;
    int g = tid >> 2;
    int v = g % 25, th = g / 25;
    int tb = th * 8;
    float acc[8][4];
    if (b == 0)      conv5<1>(sIn, sW, *(const float4*)&b2[o4],      o4, v, tb, acc);
    else if (b == 1) conv5<2>(sIn, sW, *(const float4*)&b2[16 + o4], o4, v, tb, acc);
    else {
      #pragma unroll
      for (int s = 0; s < 8; s++)
        #pragma unroll
        for (int j = 0; j < 4; j++) {
          int o = o4 + j, r = tb + s + 4;
          float a = sIn[(o * 24 + r - 1) * 25 + v];
          float m = sIn[(o * 24 + r    ) * 25 + v];
          float c = sIn[(o * 24 + r + 1) * 25 + v];
          acc[s][j] = fmaxf(fmaxf(a, m), c);
        }
    }
    #pragma unroll
    for (int s = 0; s < 8; s++) {
      int gt = t0 + tb + s;
      #pragma unroll
      for (int j = 0; j < 4; j++) {
        float val = acc[s][j];
        zbB[(((b * 32 + n) * 512 + gt) * 16 + (o4 + j)) * 25 + v] = (bf16)val;
        po[j] += val; pq[j] += val * val;
      }
    }
  }
  #pragma unroll
  for (int m = 4; m < 64; m <<= 1) {
    #pragma unroll
    for (int j = 0; j < 4; j++) { po[j] += __shfl_xor(po[j], m); pq[j] += __shfl_xor(pq[j], m); }
  }
  int lane = tid & 63, w = tid >> 6;
  if (lane < 4) {
    #pragma unroll
    for (int j = 0; j < 4; j++) { sRedS[w][lane][j] = po[j]; sRedQ[w][lane][j] = pq[j]; }
  }
  __syncthreads();
  if (tid < 16) {
    int o = tid, txo = o >> 2, j = o & 3;
    float s = 0.f, q = 0.f;
    #pragma unroll
    for (int ww = 0; ww < 4; ww++) { s += sRedS[ww][txo][j]; q += sRedQ[ww][txo][j]; }
    int pidx = (n * 32 + tt) * 48 + b * 16 + o;
    pSum2[pidx] = s; pSq2[pidx] = q;
  }
}

// ------------------------------------------------------------------
// Kernel 7: concat + bn + residual + relu. Block per (n, 8-t chunk).
// ------------------------------------------------------------------
__global__ __launch_bounds__(256, 8)
void k7_final(const float* __restrict__ x, const bf16* __restrict__ preB,
              const bf16* __restrict__ zbB,
              const float* __restrict__ sc1, const float* __restrict__ sh1,
              const float* __restrict__ sc2, const float* __restrict__ sh2,
              float* __restrict__ out)
{
  const int bid = blockIdx.x;            // 2048 = 32 n * 64 chunks
  const int n = bid >> 6, tc = bid & 63;
  const int t0 = tc * 8;
  for (int e = threadIdx.x; e < 12800; e += 256) {
    int ch = e / 200, r = e - ch * 200;
    int tl = r / 25, v = r - tl * 25;
    int t = t0 + tl;
    int b = ch >> 4, o = ch & 15;
    float val;
    if (b < 3) {
      val = sc2[b * 16 + o] * (float)zbB[(((b * 32 + n) * 512 + t) * 16 + o) * 25 + v]
          + sh2[b * 16 + o];
    } else {
      int ko = 48 + o;
      val = sc1[ko] * (float)preB[((n * 512 + t) * 64 + ko) * 25 + v] + sh1[ko];
    }
    int ax = (n * 64 + ch) * 12800 + t * 25 + v;
    out[ax] = fmaxf(val + x[ax], 0.f);
  }
}

// ------------------------------------------------------------------
extern "C" void kernel_launch(void* const* d_in, const int* in_sizes, int n_in,
                              void* d_out, int out_size, void* d_ws, size_t ws_size,
                              hipStream_t stream)
{
  const float* x       = (const float*)d_in[0];
  const float* topo    = (const float*)d_in[1];
  const float* ln_g    = (const float*)d_in[2];
  const float* ln_b    = (const float*)d_in[3];
  const float* qk_w    = (const float*)d_in[4];
  const float* qk_b    = (const float*)d_in[5];
  const float* convd_w = (const float*)d_in[6];
  const float* convd_b = (const float*)d_in[7];
  const float* sagc_g  = (const float*)d_in[8];
  const float* sagc_b  = (const float*)d_in[9];
  const float* w1      = (const float*)d_in[10];
  const float* b1      = (const float*)d_in[11];
  const float* bn1_g   = (const float*)d_in[12];
  const float* bn1_b   = (const float*)d_in[13];
  const float* w2      = (const float*)d_in[14];
  const float* b2      = (const float*)d_in[15];
  const float* bn2_g   = (const float*)d_in[16];
  const float* bn2_b   = (const float*)d_in[17];
  float* out = (float*)d_out;
  float* ws  = (float*)d_ws;

  bf16*  preB  = (bf16*)ws;                    // 26,214,400 bf16
  bf16*  zbB   = (bf16*)(ws + 13107200);       // 19,660,800 bf16
  float* pSum1 = ws + 22937600;                // 1,048,576
  float* pSq1  = ws + 23986176;                // 1,048,576
  float* pSum2 = ws + 25034752;                // 49,152
  float* pSq2  = ws + 25083904;                // 49,152
  float* scS   = ws + 25133056;  float* shS = scS + 64;
  float* sc1   = scS + 128;      float* sh1 = scS + 192;
  float* sc2   = scS + 256;      float* sh2 = scS + 304;
  bf16*  qkB   = (bf16*)(ws + 25133440);       // 6144 bf16
  bf16*  convB = (bf16*)(ws + 25136512);       // 12288 bf16
  bf16*  w1B   = (bf16*)(ws + 25142656);       // 8192 bf16
  float* oS1   = ws + 25146752;                // 16384
  float* oQ1   = ws + 25163136;                // 16384
  bf16*  saB   = (bf16*)d_out;                 // d_out doubles as sa scratch

  const float invN = 1.f / 409600.f;   // N*T*V

  kprepack<<<10, 256, 0, stream>>>(qk_w, convd_w, w1, qkB, convB, w1B);
  k1_sa_sagc<<<dim3(512, 32), 256, 0, stream>>>(x, topo, ln_g, ln_b, qk_b,
                                                qkB, convB, convd_b, saB, pSum1, pSq1);
  kpart<<<256, 256, 0, stream>>>(pSum1, pSq1, oS1, oQ1);
  kreduce<<<64, 256, 0, stream>>>(oS1, oQ1, 256, 64, invN, sagc_g, sagc_b, scS, shS);
  k3_ygc_pre<<<dim3(512, 32), 256, 0, stream>>>(x, saB, scS, shS, w1B, b1,
                                                preB, pSum1, pSq1);
  kpart<<<256, 256, 0, stream>>>(pSum1, pSq1, oS1, oQ1);
  kreduce<<<64, 256, 0, stream>>>(oS1, oQ1, 256, 64, invN, bn1_g, bn1_b, sc1, sh1);
  k5_tcn_branch<<<dim3(32, 3, 32), 256, 0, stream>>>(preB, sc1, sh1, w2, b2,
                                                     zbB, pSum2, pSq2);
  kreduce<<<48, 256, 0, stream>>>(pSum2, pSq2, 1024, 48, invN, bn2_g, bn2_b, sc2, sh2);
  k7_final<<<2048, 256, 0, stream>>>(x, preB, zbB, sc1, sh1, sc2, sh2, out);
}

// Round 14
// 335.013 us; speedup vs baseline: 2.3387x; 1.0048x over previous
//
#include <hip/hip_runtime.h>

// EncodingBlock — Round 14: round-13 base + k1 weight-load early-issue.
//  VGPR_Count=36 proved hipcc issues qkB/convB fragment loads AT USE (P3/P6),
//  putting ~200cy L2 latency on the serialized phase chain. This round issues
//  them at the earliest legal point: qkB frags + qk_b right after P1's x loads
//  (consumed 2 phases later), convB frags + convd_b at P5 entry (consumed in
//  P6). Peak VGPR ~68 <= 73 (7 waves/SIMD preserved). All math identical.
//  Everything else = round-13 verbatim (verified 335.4/336.3/336.6 µs).

#define EPS 1e-5f

typedef __bf16 bf16;
typedef __bf16 bf16x8 __attribute__((ext_vector_type(8)));
typedef float f32x4 __attribute__((ext_vector_type(4)));

// ------------------------------------------------------------------
// Prepack weights to MFMA B-fragments.
// ------------------------------------------------------------------
__global__ void kprepack(const float* __restrict__ qk_w, const float* __restrict__ convd_w,
                         const float* __restrict__ w1g,
                         bf16* __restrict__ qkB, bf16* __restrict__ convB, bf16* __restrict__ w1B)
{
  int gid = blockIdx.x * 256 + threadIdx.x;
  if (gid < 384) {                       // qk: (nt,ks,lane) 3*2*64, hi/lo
    int lane = gid & 63, f = gid >> 6;
    int nt = f >> 1, ks = f & 1;
    int row = nt * 16 + (lane & 15);
    int col = ks * 32 + ((lane >> 4) * 8);
    const float* src = &qk_w[row * 64 + col];
    bf16* dh = &qkB[(f * 64 + lane) * 8];
    bf16* dl = dh + 3072;
    #pragma unroll
    for (int j = 0; j < 8; j++) {
      float w = src[j];
      bf16 h = (bf16)w;
      dh[j] = h;
      dl[j] = (bf16)(w - (float)h);
    }
  } else if (gid < 1920) {               // convd: (nt,ks,lane) 4*6*64
    int g = gid - 384;
    int lane = g & 63, f = g >> 6;
    int nt = f / 6, ks = f - nt * 6;
    int k0 = ks * 32 + ((lane >> 4) * 8);
    int h = k0 >> 6, c = k0 & 63;
    int o = nt * 16 + (lane & 15);
    const float* src = &convd_w[(h * 64 + o) * 64 + c];
    bf16* d = &convB[(f * 64 + lane) * 8];
    #pragma unroll
    for (int j = 0; j < 8; j++) d[j] = (bf16)src[j];
  } else if (gid < 2432) {               // w1: (nt,ks,lane) 4*2*64, hi/lo
    int g = gid - 1920;
    int lane = g & 63, f = g >> 6;
    int nt = f >> 1, ks = f & 1;
    int ko = nt * 16 + (lane & 15);
    int c0 = ks * 32 + ((lane >> 4) * 8);
    const float* src = &w1g[ko * 64 + c0];
    bf16* dh = &w1B[(f * 64 + lane) * 8];
    bf16* dl = dh + 4096;
    #pragma unroll
    for (int j = 0; j < 8; j++) {
      float w = src[j];
      bf16 h = (bf16)w;
      dh[j] = h;
      dl[j] = (bf16)(w - (float)h);
    }
  }
}

// ------------------------------------------------------------------
// Kernel 1: fused SelfAttention + SA_GC (pre-BN). LDS 21.5 KB -> 7/CU.
// Weight fragments early-issued into VGPRs to hide L2 latency.
// ------------------------------------------------------------------
__global__ __launch_bounds__(256, 7)
void k1_sa_sagc(const float* __restrict__ x,
                const float* __restrict__ topo,
                const float* __restrict__ ln_g, const float* __restrict__ ln_b,
                const float* __restrict__ qk_b,
                const bf16* __restrict__ qkB, const bf16* __restrict__ convB,
                const float* __restrict__ convd_b,
                bf16* __restrict__ saB, float* __restrict__ pSum, float* __restrict__ pSq)
{
  const int t = blockIdx.x, n = blockIdx.y, tid = threadIdx.x;
  const int blk = n * 512 + t;
  const int lane = tid & 63, wave = tid >> 6;
  const int rr = lane & 15, co = (lane >> 4) * 8, rq = (lane >> 4) * 4;

  __shared__ __align__(16) float smem[5512];
  bf16*  featT  = (bf16*)smem;               // [64][40] bf16     [0,1280)
  float* yF     = smem + 1280;               // [25][69] f32      [1280,3005)  slot B
  bf16*  sAttn  = (bf16*)(smem + 1280);      // [75][40] bf16     overlay of yF (P4-P5)
  float* sPartS = smem + 3008;               // [25*4]            slot C
  float* sPartQ = smem + 3208;
  float* sLnG   = smem + 3408;               // [64]
  float* sLnB   = smem + 3472;               // [64]
  float* sQK    = smem + 3008;               // [25][56] f32      overlay (P3-P4)
  bf16*  zL     = (bf16*)(smem + 3008);      // [25][200] bf16    overlay (P5-P6)

  // P1: load x (coalesced, kept in regs), featT bf16, LN partials
  const int v = tid & 31, cb = tid >> 5;
  float xv[8];
  {
    const float* xp = &x[((n * 64 + cb) * 512 + t) * 25 + (v < 25 ? v : 0)];
    float s = 0.f, q = 0.f;
    #pragma unroll
    for (int k = 0; k < 8; k++) {
      float f = (v < 25) ? xp[k * 102400] : 0.f;   // 102400 = 8*512*25
      xv[k] = f;
      featT[(cb + 8 * k) * 40 + v] = (bf16)f;
      s += f; q += f * f;
    }
    s += __shfl_xor(s, 32); q += __shfl_xor(q, 32);
    if (lane < 32 && v < 25) { sPartS[v * 4 + wave] = s; sPartQ[v * 4 + wave] = q; }
    if (tid < 64) { sLnG[tid] = ln_g[tid]; sLnB[tid] = ln_b[tid]; }
    if (tid < 64) {
      #pragma unroll
      for (int j = 25; j < 32; j++) featT[tid * 40 + j] = (bf16)0.f;
    }
  }

  // EARLY ISSUE: qkB fragments + qk_b for P3 (consumed 2 phases later;
  // latency hides under P1 LDS stores + barrier + P2 LN math).
  bf16x8 WBh[2][2], WBl[2][2];
  float qbr[2];
  {
    #pragma unroll
    for (int q = 0; q < 2; q++) {
      if (wave >= 2 && q > 0) break;
      int nt = (wave < 2) ? (q * 2) : 1;
      #pragma unroll
      for (int ks = 0; ks < 2; ks++) {
        WBh[q][ks] = *(const bf16x8*)&qkB[((nt * 2 + ks) * 64 + lane) * 8];
        WBl[q][ks] = *(const bf16x8*)&qkB[3072 + ((nt * 2 + ks) * 64 + lane) * 8];
      }
      qbr[q] = qk_b[nt * 16 + rr];
    }
  }
  __syncthreads();

  // P2: finalize LN stats (redundant per thread) + y -> yF f32 (conflict-free)
  if (v < 25) {
    float S = sPartS[v * 4] + sPartS[v * 4 + 1] + sPartS[v * 4 + 2] + sPartS[v * 4 + 3];
    float Q = sPartQ[v * 4] + sPartQ[v * 4 + 1] + sPartQ[v * 4 + 2] + sPartQ[v * 4 + 3];
    float mu = S * (1.f / 64.f);
    float rstd = rsqrtf(Q * (1.f / 64.f) - mu * mu + EPS);
    #pragma unroll
    for (int k = 0; k < 8; k++) {
      int c = cb + 8 * k;
      yF[v * 69 + c] = (xv[k] - mu) * rstd * sLnG[c] + sLnB[c];
    }
  }
  __syncthreads();

  // P3: QK projection via MFMA; hi/lo split computed in-register from yF.
  {
    const int mt = wave & 1;
    const int r0 = mt * 16 + rr;               // rows >=25 read junk -> discarded C rows
    bf16x8 Ah[2], Al[2];
    #pragma unroll
    for (int ks = 0; ks < 2; ks++) {
      const float* yp = &yF[r0 * 69 + ks * 32 + co];
      #pragma unroll
      for (int j = 0; j < 8; j++) {
        float yv = yp[j];
        bf16 h = (bf16)yv;
        Ah[ks][j] = h;
        Al[ks][j] = (bf16)(yv - (float)h);
      }
    }
    #pragma unroll
    for (int q = 0; q < 2; q++) {
      if (wave >= 2 && q > 0) break;
      int nt = (wave < 2) ? (q * 2) : 1;
      f32x4 acc = {qbr[q], qbr[q], qbr[q], qbr[q]};
      #pragma unroll
      for (int ks = 0; ks < 2; ks++) {
        acc = __builtin_amdgcn_mfma_f32_16x16x32_bf16(Ah[ks], WBh[q][ks], acc, 0, 0, 0);
        acc = __builtin_amdgcn_mfma_f32_16x16x32_bf16(Ah[ks], WBl[q][ks], acc, 0, 0, 0);
        acc = __builtin_amdgcn_mfma_f32_16x16x32_bf16(Al[ks], WBh[q][ks], acc, 0, 0, 0);
      }
      #pragma unroll
      for (int r = 0; r < 4; r++) {
        int i = mt * 16 + rq + r;
        if (i < 25) sQK[i * 56 + nt * 16 + rr] = acc[r];
      }
    }
  }
  __syncthreads();

  // P4: dots + softmax + *topo -> sAttn bf16 [75][40]; 2 threads per (h,i) row
  if (tid < 150) {
    int p = tid >> 1, half = tid & 1;
    int h = p / 25, i = p - (p / 25) * 25;
    const float* qr = &sQK[i * 56 + h * 8];
    float4 qa = *(const float4*)qr, qb4 = *(const float4*)(qr + 4);
    const int j0 = half * 13;
    const int cnt = 13 - half;
    float lgv[13];
    float lmax = -3.4e38f;
    #pragma unroll
    for (int jj = 0; jj < 13; jj++) {
      int j = j0 + jj; j = j > 24 ? 24 : j;
      const float* kr = &sQK[j * 56 + 24 + h * 8];
      float4 ka = *(const float4*)kr, kb = *(const float4*)(kr + 4);
      float d = qa.x * ka.x + qa.y * ka.y + qa.z * ka.z + qa.w * ka.w
              + qb4.x * kb.x + qb4.y * kb.y + qb4.z * kb.z + qb4.w * kb.w;
      d *= 0.35355339059327373f;
      lgv[jj] = d;
      lmax = fmaxf(lmax, d);
    }
    lmax = fmaxf(lmax, __shfl_xor(lmax, 1));
    float se = 0.f;
    #pragma unroll
    for (int jj = 0; jj < 13; jj++) {
      float e = __expf(lgv[jj] - lmax);
      lgv[jj] = e;
      if (jj < cnt) se += e;
    }
    se += __shfl_xor(se, 1);
    float inv = 1.f / se;
    bf16* ar = &sAttn[(h * 25 + i) * 40];
    #pragma unroll
    for (int jj = 0; jj < 13; jj++) {
      int j = j0 + jj;
      if (jj < cnt) ar[j] = (bf16)(lgv[jj] * inv * topo[(h * 25 + i) * 25 + j]);
    }
    if (half) {
      #pragma unroll
      for (int j = 25; j < 32; j++) ar[j] = (bf16)0.f;   // K-dim pad must be zero
    }
  }
  __syncthreads();

  // EARLY ISSUE: convB fragments + bias for P6 (consumed next phase;
  // latency hides under P5's tr-reads + MFMAs + barrier).
  bf16x8 WCv[6];
  float cb2;
  {
    const int o = wave * 16 + rr;
    #pragma unroll
    for (int ks = 0; ks < 6; ks++)
      WCv[ks] = *(const bf16x8*)&convB[((wave * 6 + ks) * 64 + lane) * 8];
    cb2 = convd_b[o] + convd_b[64 + o] + convd_b[128 + o];
  }

  // P5: z = A_h @ feat via MFMA; wave owns 16 feat-cols; zL [25][200]
  {
    const int nt = wave;
    bf16x8 Bf = *(const bf16x8*)&featT[(nt * 16 + rr) * 40 + co];
    #pragma unroll
    for (int h = 0; h < 3; h++) {
      #pragma unroll
      for (int mt = 0; mt < 2; mt++) {
        bf16x8 Af = *(const bf16x8*)&sAttn[(h * 25 + mt * 16 + rr) * 40 + co];
        f32x4 az = {0.f, 0.f, 0.f, 0.f};
        az = __builtin_amdgcn_mfma_f32_16x16x32_bf16(Af, Bf, az, 0, 0, 0);
        #pragma unroll
        for (int r = 0; r < 4; r++) {
          int i = mt * 16 + rq + r;
          if (i < 25) zL[i * 200 + h * 64 + nt * 16 + rr] = (bf16)az[r];
        }
      }
    }
  }
  __syncthreads();

  // P6: sa = z @ Wcat via MFMA; direct global store + shfl BN partials
  {
    const int nt = wave;
    int o = nt * 16 + rr;
    float po = 0.f, pq = 0.f;
    #pragma unroll
    for (int mt = 0; mt < 2; mt++) {
      int zr = mt * 16 + rr;
      zr = (zr < 25) ? zr : 0;                 // clamp: stay inside zL allocation
      f32x4 acc = {cb2, cb2, cb2, cb2};
      #pragma unroll
      for (int ks = 0; ks < 6; ks++) {
        bf16x8 Az = *(const bf16x8*)&zL[zr * 200 + ks * 32 + co];
        acc = __builtin_amdgcn_mfma_f32_16x16x32_bf16(Az, WCv[ks], acc, 0, 0, 0);
      }
      #pragma unroll
      for (int r = 0; r < 4; r++) {
        int i = mt * 16 + rq + r;
        if (i < 25) {
          float val = acc[r];
          saB[blk * 1600 + o * 25 + i] = (bf16)val;
          po += val; pq += val * val;
        }
      }
    }
    po += __shfl_xor(po, 16); pq += __shfl_xor(pq, 16);
    po += __shfl_xor(po, 32); pq += __shfl_xor(pq, 32);
    if (lane < 16) {
      pSum[blk * 64 + o] = po;
      pSq [blk * 64 + o] = pq;
    }
  }
}

// ------------------------------------------------------------------
// kpart: coalesced first-level reduce of [16384][64] partials -> [256][64]
// ------------------------------------------------------------------
__global__ __launch_bounds__(256, 8)
void kpart(const float* __restrict__ pS, const float* __restrict__ pQ,
           float* __restrict__ oS, float* __restrict__ oQ)
{
  const int g = blockIdx.x, tid = threadIdx.x;
  const int c = tid & 63, r = tid >> 6;
  float s = 0.f, q = 0.f;
  for (int i = 0; i < 16; i++) {
    int b = g * 64 + r * 16 + i;
    s += pS[b * 64 + c]; q += pQ[b * 64 + c];
  }
  __shared__ float ls[4][64], lq[4][64];
  ls[r][c] = s; lq[r][c] = q;
  __syncthreads();
  if (tid < 64) {
    oS[g * 64 + tid] = ls[0][tid] + ls[1][tid] + ls[2][tid] + ls[3][tid];
    oQ[g * 64 + tid] = lq[0][tid] + lq[1][tid] + lq[2][tid] + lq[3][tid];
  }
}

// ------------------------------------------------------------------
// BN-stat reduce: one block per channel; partials layout [part][C]
// ------------------------------------------------------------------
__global__ __launch_bounds__(256, 4)
void kreduce(const float* __restrict__ pS, const float* __restrict__ pQ,
             int npart, int C, float invN,
             const float* __restrict__ g, const float* __restrict__ bta,
             float* __restrict__ sc, float* __restrict__ sh)
{
  int c = blockIdx.x, tid = threadIdx.x;
  float s = 0.f, q = 0.f;
  for (int i = tid; i < npart; i += 256) { s += pS[i * C + c]; q += pQ[i * C + c]; }
  #pragma unroll
  for (int m = 1; m < 64; m <<= 1) { s += __shfl_xor(s, m); q += __shfl_xor(q, m); }
  __shared__ float rs[4], rq[4];
  int w = tid >> 6;
  if ((tid & 63) == 0) { rs[w] = s; rq[w] = q; }
  __syncthreads();
  if (tid == 0) {
    float S = rs[0] + rs[1] + rs[2] + rs[3];
    float Q = rq[0] + rq[1] + rq[2] + rq[3];
    float mu = S * invN, var = Q * invN - mu * mu;
    float r = rsqrtf(var + EPS);
    sc[c] = g[c] * r;
    sh[c] = bta[c] - mu * g[c] * r;
  }
}

// ------------------------------------------------------------------
// Kernel 3: y_gc = relu(bn(sa)+x); pre = y_gc @ W1 + b1 via MFMA (hi/lo)
// ------------------------------------------------------------------
__global__ __launch_bounds__(256, 8)
void k3_ygc_pre(const float* __restrict__ x, const bf16* __restrict__ saB,
                const float* __restrict__ scS, const float* __restrict__ shS,
                const bf16* __restrict__ w1B, const float* __restrict__ b1,
                bf16* __restrict__ preB, float* __restrict__ pSum, float* __restrict__ pSq)
{
  const int t = blockIdx.x, n = blockIdx.y, tid = threadIdx.x;
  const int blk = n * 512 + t;
  const int lane = tid & 63, wave = tid >> 6;
  const int rr = lane & 15, co = (lane >> 4) * 8, rq = (lane >> 4) * 4;

  __shared__ __align__(16) float smem[3656];
  bf16*  yH   = (bf16*)smem;             // [25][72] bf16 -> [0, 900)
  bf16*  yL   = (bf16*)(smem + 900);     // [900, 1800)
  float* sPre = smem + 1800;             // [64][29] [1800, 3656)

  if (tid < 200) {
    int lin = tid * 8;
    int c = lin / 25, v = lin - c * 25;
    bf16x8 s8 = *(const bf16x8*)&saB[blk * 1600 + lin];
    #pragma unroll
    for (int e = 0; e < 8; e++) {
      float val = scS[c] * (float)s8[e] + shS[c] + x[((n * 64 + c) * 512 + t) * 25 + v];
      val = fmaxf(val, 0.f);
      bf16 h = (bf16)val;
      yH[v * 72 + c] = h;
      yL[v * 72 + c] = (bf16)(val - (float)h);
      if (++v == 25) { v = 0; c++; }
    }
  }
  __syncthreads();

  {
    const int nt = wave;  // output cols nt*16..+15
    bf16x8 Ah[2][2], Al[2][2];
    #pragma unroll
    for (int mt = 0; mt < 2; mt++) {
      int r0 = mt * 16 + rr;               // rows >=25 read junk -> discarded
      #pragma unroll
      for (int ks = 0; ks < 2; ks++) {
        Ah[mt][ks] = *(const bf16x8*)&yH[r0 * 72 + ks * 32 + co];
        Al[mt][ks] = *(const bf16x8*)&yL[r0 * 72 + ks * 32 + co];
      }
    }
    float bb = b1[nt * 16 + rr];
    #pragma unroll
    for (int mt = 0; mt < 2; mt++) {
      f32x4 acc = {bb, bb, bb, bb};
      #pragma unroll
      for (int ks = 0; ks < 2; ks++) {
        bf16x8 Bh = *(const bf16x8*)&w1B[((nt * 2 + ks) * 64 + lane) * 8];
        bf16x8 Bl = *(const bf16x8*)&w1B[4096 + ((nt * 2 + ks) * 64 + lane) * 8];
        acc = __builtin_amdgcn_mfma_f32_16x16x32_bf16(Ah[mt][ks], Bh, acc, 0, 0, 0);
        acc = __builtin_amdgcn_mfma_f32_16x16x32_bf16(Ah[mt][ks], Bl, acc, 0, 0, 0);
        acc = __builtin_amdgcn_mfma_f32_16x16x32_bf16(Al[mt][ks], Bh, acc, 0, 0, 0);
      }
      #pragma unroll
      for (int r = 0; r < 4; r++) {
        int i = mt * 16 + rq + r;
        if (i < 25) sPre[(nt * 16 + rr) * 29 + i] = acc[r];
      }
    }
  }
  __syncthreads();

  if (tid < 200) {
    int lin = tid * 8;
    bf16x8 p8;
    #pragma unroll
    for (int e = 0; e < 8; e++) {
      int q = lin + e, ko = q / 25, v = q - ko * 25;
      p8[e] = (bf16)sPre[ko * 29 + v];
    }
    *(bf16x8*)&preB[blk * 1600 + lin] = p8;
  }
  if (tid < 64) {
    float s = 0.f, q = 0.f;
    #pragma unroll
    for (int i = 0; i < 25; i++) { float v = sPre[tid * 29 + i]; s += v; q += v * v; }
    pSum[blk * 64 + tid] = s;
    pSq [blk * 64 + tid] = q;
  }
}

// ------------------------------------------------------------------
// Kernel 5: TCN branches; preB [n][t][ch][v], zbB [b][n][t][o][v]
// Single-stage 16-ch staging (44KB LDS, 3 blocks/CU) — measured best.
// ------------------------------------------------------------------
template<int D>
__device__ __forceinline__ void conv5(const float* __restrict__ sIn, const float* __restrict__ sW,
                                      float4 bias, int o4, int v, int tb, float acc[8][4])
{
  #pragma unroll
  for (int s = 0; s < 8; s++) {
    acc[s][0] = bias.x; acc[s][1] = bias.y; acc[s][2] = bias.z; acc[s][3] = bias.w;
  }
  const int NW = 8 + 4 * D;
  for (int ic = 0; ic < 16; ic++) {
    float4 wk[5];
    #pragma unroll
    for (int kt = 0; kt < 5; kt++) wk[kt] = *(const float4*)&sW[(ic * 5 + kt) * 16 + o4];
    float xw[8 + 4 * D];
    #pragma unroll
    for (int w = 0; w < NW; w++) xw[w] = sIn[(ic * 24 + (tb - 2 * D + w + 4)) * 25 + v];
    #pragma unroll
    for (int s = 0; s < 8; s++)
      #pragma unroll
      for (int kt = 0; kt < 5; kt++) {
        float xv = xw[s + kt * D];
        acc[s][0] += xv * wk[kt].x; acc[s][1] += xv * wk[kt].y;
        acc[s][2] += xv * wk[kt].z; acc[s][3] += xv * wk[kt].w;
      }
  }
}

__global__ __launch_bounds__(256, 3)
void k5_tcn_branch(const bf16* __restrict__ preB,
                   const float* __restrict__ sc1, const float* __restrict__ sh1,
                   const float* __restrict__ w2, const float* __restrict__ b2,
                   bf16* __restrict__ zbB, float* __restrict__ pSum2, float* __restrict__ pSq2)
{
  const int tt = blockIdx.x, b = blockIdx.y, n = blockIdx.z;
  const int tid = threadIdx.x, t0 = tt * 16;
  __shared__ __align__(16) float sIn[16 * 24 * 25];
  __shared__ __align__(16) float sW[16 * 5 * 16];
  __shared__ float sRedS[4][4][4], sRedQ[4][4][4];

  for (int idx = tid; idx < 1200; idx += 256) {
    int r = idx / 50, k8 = idx - r * 50;
    int gt = t0 - 4 + r;
    int lin = k8 * 8;
    if (gt >= 0 && gt < 512) {
      bf16x8 p8 = *(const bf16x8*)&preB[((n * 512 + gt) * 64 + b * 16) * 25 + lin];
      #pragma unroll
      for (int e = 0; e < 8; e++) {
        int q = lin + e, ic = q / 25, v = q - ic * 25;
        int ch = b * 16 + ic;
        sIn[(ic * 24 + r) * 25 + v] = fmaxf(sc1[ch] * (float)p8[e] + sh1[ch], 0.f);
      }
    } else {
      #pragma unroll
      for (int e = 0; e < 8; e++) {
        int q = lin + e, ic = q / 25, v = q - ic * 25;
        sIn[(ic * 24 + r) * 25 + v] = 0.f;
      }
    }
  }
  if (b < 2)
    for (int idx = tid; idx < 1280; idx += 256) {
      int o = idx / 80, rem = idx - o * 80;
      int ic = rem / 5, kt = rem - ic * 5;
      sW[(ic * 5 + kt) * 16 + o] = w2[((b * 16 + o) * 16 + ic) * 5 + kt];
    }
  __syncthreads();

  float po[4] = {0.f, 0.f, 0.f, 0.f}, pq[4] = {0.f, 0.f, 0.f, 0.f};
  if (tid < 200) {
    int tx = tid & 3, o4 = tx * 4;
    int g = tid >> 2;
    int v = g % 25, th = g / 25;
    int tb = th * 8;
    float acc[8][4];
    if (b == 0)      conv5<1>(sIn, sW, *(const float4*)&b2[o4],      o4, v, tb, acc);
    else if (b == 1) conv5<2>(sIn, sW, *(const float4*)&b2[16 + o4], o4, v, tb, acc);
    else {
      #pragma unroll
      for (int s = 0; s < 8; s++)
        #pragma unroll
        for (int j = 0; j < 4; j++) {
          int o = o4 + j, r = tb + s + 4;
          float a = sIn[(o * 24 + r - 1) * 25 + v];
          float m = sIn[(o * 24 + r    ) * 25 + v];
          float c = sIn[(o * 24 + r + 1) * 25 + v];
          acc[s][j] = fmaxf(fmaxf(a, m), c);
        }
    }
    #pragma unroll
    for (int s = 0; s < 8; s++) {
      int gt = t0 + tb + s;
      #pragma unroll
      for (int j = 0; j < 4; j++) {
        float val = acc[s][j];
        zbB[(((b * 32 + n) * 512 + gt) * 16 + (o4 + j)) * 25 + v] = (bf16)val;
        po[j] += val; pq[j] += val * val;
      }
    }
  }
  #pragma unroll
  for (int m = 4; m < 64; m <<= 1) {
    #pragma unroll
    for (int j = 0; j < 4; j++) { po[j] += __shfl_xor(po[j], m); pq[j] += __shfl_xor(pq[j], m); }
  }
  int lane = tid & 63, w = tid >> 6;
  if (lane < 4) {
    #pragma unroll
    for (int j = 0; j < 4; j++) { sRedS[w][lane][j] = po[j]; sRedQ[w][lane][j] = pq[j]; }
  }
  __syncthreads();
  if (tid < 16) {
    int o = tid, txo = o >> 2, j = o & 3;
    float s = 0.f, q = 0.f;
    #pragma unroll
    for (int ww = 0; ww < 4; ww++) { s += sRedS[ww][txo][j]; q += sRedQ[ww][txo][j]; }
    int pidx = (n * 32 + tt) * 48 + b * 16 + o;
    pSum2[pidx] = s; pSq2[pidx] = q;
  }
}

// ------------------------------------------------------------------
// Kernel 7: concat + bn + residual + relu. Block per (n, 8-t chunk).
// ------------------------------------------------------------------
__global__ __launch_bounds__(256, 8)
void k7_final(const float* __restrict__ x, const bf16* __restrict__ preB,
              const bf16* __restrict__ zbB,
              const float* __restrict__ sc1, const float* __restrict__ sh1,
              const float* __restrict__ sc2, const float* __restrict__ sh2,
              float* __restrict__ out)
{
  const int bid = blockIdx.x;            // 2048 = 32 n * 64 chunks
  const int n = bid >> 6, tc = bid & 63;
  const int t0 = tc * 8;
  for (int e = threadIdx.x; e < 12800; e += 256) {
    int ch = e / 200, r = e - ch * 200;
    int tl = r / 25, v = r - tl * 25;
    int t = t0 + tl;
    int b = ch >> 4, o = ch & 15;
    float val;
    if (b < 3) {
      val = sc2[b * 16 + o] * (float)zbB[(((b * 32 + n) * 512 + t) * 16 + o) * 25 + v]
          + sh2[b * 16 + o];
    } else {
      int ko = 48 + o;
      val = sc1[ko] * (float)preB[((n * 512 + t) * 64 + ko) * 25 + v] + sh1[ko];
    }
    int ax = (n * 64 + ch) * 12800 + t * 25 + v;
    out[ax] = fmaxf(val + x[ax], 0.f);
  }
}

// ------------------------------------------------------------------
extern "C" void kernel_launch(void* const* d_in, const int* in_sizes, int n_in,
                              void* d_out, int out_size, void* d_ws, size_t ws_size,
                              hipStream_t stream)
{
  const float* x       = (const float*)d_in[0];
  const float* topo    = (const float*)d_in[1];
  const float* ln_g    = (const float*)d_in[2];
  const float* ln_b    = (const float*)d_in[3];
  const float* qk_w    = (const float*)d_in[4];
  const float* qk_b    = (const float*)d_in[5];
  const float* convd_w = (const float*)d_in[6];
  const float* convd_b = (const float*)d_in[7];
  const float* sagc_g  = (const float*)d_in[8];
  const float* sagc_b  = (const float*)d_in[9];
  const float* w1      = (const float*)d_in[10];
  const float* b1      = (const float*)d_in[11];
  const float* bn1_g   = (const float*)d_in[12];
  const float* bn1_b   = (const float*)d_in[13];
  const float* w2      = (const float*)d_in[14];
  const float* b2      = (const float*)d_in[15];
  const float* bn2_g   = (const float*)d_in[16];
  const float* bn2_b   = (const float*)d_in[17];
  float* out = (float*)d_out;
  float* ws  = (float*)d_ws;

  bf16*  preB  = (bf16*)ws;                    // 26,214,400 bf16
  bf16*  zbB   = (bf16*)(ws + 13107200);       // 19,660,800 bf16
  float* pSum1 = ws + 22937600;                // 1,048,576
  float* pSq1  = ws + 23986176;                // 1,048,576
  float* pSum2 = ws + 25034752;                // 49,152
  float* pSq2  = ws + 25083904;                // 49,152
  float* scS   = ws + 25133056;  float* shS = scS + 64;
  float* sc1   = scS + 128;      float* sh1 = scS + 192;
  float* sc2   = scS + 256;      float* sh2 = scS + 304;
  bf16*  qkB   = (bf16*)(ws + 25133440);       // 6144 bf16
  bf16*  convB = (bf16*)(ws + 25136512);       // 12288 bf16
  bf16*  w1B   = (bf16*)(ws + 25142656);       // 8192 bf16
  float* oS1   = ws + 25146752;                // 16384
  float* oQ1   = ws + 25163136;                // 16384
  bf16*  saB   = (bf16*)d_out;                 // d_out doubles as sa scratch

  const float invN = 1.f / 409600.f;   // N*T*V

  kprepack<<<10, 256, 0, stream>>>(qk_w, convd_w, w1, qkB, convB, w1B);
  k1_sa_sagc<<<dim3(512, 32), 256, 0, stream>>>(x, topo, ln_g, ln_b, qk_b,
                                                qkB, convB, convd_b, saB, pSum1, pSq1);
  kpart<<<256, 256, 0, stream>>>(pSum1, pSq1, oS1, oQ1);
  kreduce<<<64, 256, 0, stream>>>(oS1, oQ1, 256, 64, invN, sagc_g, sagc_b, scS, shS);
  k3_ygc_pre<<<dim3(512, 32), 256, 0, stream>>>(x, saB, scS, shS, w1B, b1,
                                                preB, pSum1, pSq1);
  kpart<<<256, 256, 0, stream>>>(pSum1, pSq1, oS1, oQ1);
  kreduce<<<64, 256, 0, stream>>>(oS1, oQ1, 256, 64, invN, bn1_g, bn1_b, sc1, sh1);
  k5_tcn_branch<<<dim3(32, 3, 32), 256, 0, stream>>>(preB, sc1, sh1, w2, b2,
                                                     zbB, pSum2, pSq2);
  kreduce<<<48, 256, 0, stream>>>(pSum2, pSq2, 1024, 48, invN, bn2_g, bn2_b, sc2, sh2);
  k7_final<<<2048, 256, 0, stream>>>(x, preB, zbB, sc1, sh1, sc2, sh2, out);
}